// Round 6
// baseline (498.818 us; speedup 1.0000x reference)
//
#include <hip/hip_runtime.h>
#include <hip/hip_bf16.h>
#include <math.h>

#define L_TOT 4097
#define BSZ 2
#define ROWS (BSZ*L_TOT)   // 8194
#define NSEG 128
#define SEGLEN 33          // 128*33 = 4224 >= 4097

typedef __bf16 bf16x8 __attribute__((ext_vector_type(8)));
typedef float  f32x4  __attribute__((ext_vector_type(4)));
#define ASTR 56            // LDS row stride (bf16) for BK=32 staging tiles
#define AST2 72            // LDS row stride (bf16) for BK=64 staging tiles
#define XSTR 520           // LDS row stride (bf16) for resident 512-wide tiles

__device__ __forceinline__ float sigmoidf_(float v){ return 1.0f/(1.0f+__expf(-v)); }
__device__ __forceinline__ float siluf_(float v){ return v * sigmoidf_(v); }
__device__ __forceinline__ unsigned short bfbits(float f){
    __bf16 h = (__bf16)f;
    return __builtin_bit_cast(unsigned short, h);
}

// ---------------------------------------------------------------------------
// f32 -> bf16 weight conversion (4 tensors in one launch)
// ---------------------------------------------------------------------------
__global__ __launch_bounds__(256) void cvt4(
    const float* __restrict__ w0, const float* __restrict__ w1,
    const float* __restrict__ w2, const float* __restrict__ w3,
    __bf16* __restrict__ o0, __bf16* __restrict__ o1,
    __bf16* __restrict__ o2, __bf16* __restrict__ o3)
{
    long i = ((long)blockIdx.x*256 + threadIdx.x)*8;
    const float* src; __bf16* dst; long off;
    if (i < 524288)        { src = w0; dst = o0; off = i; }
    else if (i < 1048576)  { src = w1; dst = o1; off = i - 524288; }
    else if (i < 1310720)  { src = w2; dst = o2; off = i - 1048576; }
    else if (i < 1359872)  { src = w3; dst = o3; off = i - 1310720; }
    else return;
    float4 a = *(const float4*)(src+off), b = *(const float4*)(src+off+4);
    bf16x8 o;
    o[0]=(__bf16)a.x; o[1]=(__bf16)a.y; o[2]=(__bf16)a.z; o[3]=(__bf16)a.w;
    o[4]=(__bf16)b.x; o[5]=(__bf16)b.y; o[6]=(__bf16)b.z; o[7]=(__bf16)b.w;
    *(bf16x8*)(dst+off) = o;
}

__global__ __launch_bounds__(256) void cvt_gather_x(
    const float* __restrict__ x, __bf16* __restrict__ out)
{
    long i = ((long)blockIdx.x*256 + threadIdx.x)*8;
    if (i >= 2048L*512) return;
    int row = (int)(i >> 9), col = (int)(i & 511);
    long srow = row + (row >> 10) + 1;
    const float* src = x + srow*512 + col;
    float4 a = *(const float4*)src, b = *(const float4*)(src+4);
    bf16x8 o;
    o[0]=(__bf16)a.x; o[1]=(__bf16)a.y; o[2]=(__bf16)a.z; o[3]=(__bf16)a.w;
    o[4]=(__bf16)b.x; o[5]=(__bf16)b.y; o[6]=(__bf16)b.z; o[7]=(__bf16)b.w;
    *(bf16x8*)(out+i) = o;
}

// ---------------------------------------------------------------------------
// bf16 MFMA GEMM (BM=128,BN=64,BK=32): C2[M,N] = A[M,K]*W[N,K]^T, bf16 out
// ---------------------------------------------------------------------------
__global__ __launch_bounds__(256) void gemm_bf16(
    const __bf16* __restrict__ A, const __bf16* __restrict__ W,
    __bf16* __restrict__ C2, int M, int N, int K)
{
    __shared__ __bf16 Als[128*ASTR];
    __shared__ __bf16 Wls[64*ASTR];
    const int tid = threadIdx.x;
    const int lane = tid & 63, w = tid >> 6;
    const int n0 = blockIdx.x*64, m0 = blockIdx.y*128;

    f32x4 acc[2][4] = {};
    const int arow = tid >> 1, ahalf = tid & 1;
    const int wrow = tid >> 2, wseg = tid & 3;
    const int fr = lane & 15, fc = lane >> 4;

    for (int k0 = 0; k0 < K; k0 += 32) {
        bf16x8 av0 = {}, av1 = {};
        if (m0 + arow < M) {
            const __bf16* src = A + (long)(m0+arow)*K + k0 + ahalf*16;
            av0 = *(const bf16x8*)src;
            av1 = *(const bf16x8*)(src+8);
        }
        bf16x8 wv = *(const bf16x8*)(W + (long)(n0+wrow)*K + k0 + wseg*8);
        __syncthreads();
        *(bf16x8*)&Als[arow*ASTR + ahalf*16]     = av0;
        *(bf16x8*)&Als[arow*ASTR + ahalf*16 + 8] = av1;
        *(bf16x8*)&Wls[wrow*ASTR + wseg*8]       = wv;
        __syncthreads();

        bf16x8 a0 = *(const bf16x8*)&Als[(w*32 +      fr)*ASTR + fc*8];
        bf16x8 a1 = *(const bf16x8*)&Als[(w*32 + 16 + fr)*ASTR + fc*8];
        #pragma unroll
        for (int j = 0; j < 4; j++) {
            bf16x8 bv = *(const bf16x8*)&Wls[(j*16 + fr)*ASTR + fc*8];
            acc[0][j] = __builtin_amdgcn_mfma_f32_16x16x32_bf16(a0, bv, acc[0][j], 0,0,0);
            acc[1][j] = __builtin_amdgcn_mfma_f32_16x16x32_bf16(a1, bv, acc[1][j], 0,0,0);
        }
    }
    #pragma unroll
    for (int i = 0; i < 2; i++) {
        #pragma unroll
        for (int rr = 0; rr < 4; rr++) {
            int grow = m0 + w*32 + i*16 + fc*4 + rr;
            if (grow < M) {
                #pragma unroll
                for (int j = 0; j < 4; j++)
                    C2[(long)grow*N + n0 + j*16 + fr] = (__bf16)acc[i][j][rr];
            }
        }
    }
}

// ---------------------------------------------------------------------------
// in_proj GEMM (BM=128,BN=128,BK=64, N=1024 fixed):
//   col<512 -> xhb raw bf16 [ROWS,512];  col>=512 -> zsb = silu(v) [ROWS,512]
// ---------------------------------------------------------------------------
__global__ __launch_bounds__(256) void gemm_inproj(
    const __bf16* __restrict__ A, const __bf16* __restrict__ W,
    __bf16* __restrict__ xhb, __bf16* __restrict__ zsb, int M, int K)
{
    __shared__ __bf16 Als[128*AST2];
    __shared__ __bf16 Wls[128*AST2];
    const int tid = threadIdx.x;
    const int lane = tid & 63, w = tid >> 6;
    const int n0 = blockIdx.x*128, m0 = blockIdx.y*128;
    const int fr = lane & 15, fc = lane >> 4;
    const int row2 = tid >> 1, half = tid & 1;

    f32x4 acc[2][8] = {};

    for (int k0 = 0; k0 < K; k0 += 64) {
        bf16x8 av[4], wv[4];
        const bool aok = (m0 + row2) < M;
        const __bf16* asrc = A + (long)(m0+row2)*K + k0 + half*32;
        const __bf16* wsrc = W + (long)(n0+row2)*K + k0 + half*32;
        #pragma unroll
        for (int e = 0; e < 4; e++) {
            av[e] = aok ? *(const bf16x8*)(asrc + e*8) : (bf16x8){};
            wv[e] = *(const bf16x8*)(wsrc + e*8);
        }
        __syncthreads();
        #pragma unroll
        for (int e = 0; e < 4; e++) {
            *(bf16x8*)&Als[row2*AST2 + half*32 + e*8] = av[e];
            *(bf16x8*)&Wls[row2*AST2 + half*32 + e*8] = wv[e];
        }
        __syncthreads();
        #pragma unroll
        for (int s = 0; s < 2; s++) {
            bf16x8 a0 = *(const bf16x8*)&Als[(w*32 +      fr)*AST2 + s*32 + fc*8];
            bf16x8 a1 = *(const bf16x8*)&Als[(w*32 + 16 + fr)*AST2 + s*32 + fc*8];
            #pragma unroll
            for (int j = 0; j < 8; j++) {
                bf16x8 bv = *(const bf16x8*)&Wls[(j*16 + fr)*AST2 + s*32 + fc*8];
                acc[0][j] = __builtin_amdgcn_mfma_f32_16x16x32_bf16(a0, bv, acc[0][j], 0,0,0);
                acc[1][j] = __builtin_amdgcn_mfma_f32_16x16x32_bf16(a1, bv, acc[1][j], 0,0,0);
            }
        }
    }
    const bool xhalf = (n0 < 512);
    const int cbase = xhalf ? n0 : (n0 - 512);
    #pragma unroll
    for (int i = 0; i < 2; i++) {
        #pragma unroll
        for (int rr = 0; rr < 4; rr++) {
            int grow = m0 + w*32 + i*16 + fc*4 + rr;
            if (grow < M) {
                if (xhalf) {
                    #pragma unroll
                    for (int j = 0; j < 8; j++)
                        xhb[(long)grow*512 + cbase + j*16 + fr] = (__bf16)acc[i][j][rr];
                } else {
                    #pragma unroll
                    for (int j = 0; j < 8; j++)
                        zsb[(long)grow*512 + cbase + j*16 + fr] = (__bf16)siluf_(acc[i][j][rr]);
                }
            }
        }
    }
}

// ---------------------------------------------------------------------------
// Fused xproj: dbc GEMM (xi tile resident in LDS) + delta softplus + pack.
// Block = 64 rows, 256 threads (4 waves x 16 rows).
// Writes BC[ROWS,32] f32 and pdx[ROWS,512] u32 (bf16 delta | bf16 xi << 16).
// LDS: 64x520 bf16 (65.0KB) + 48x520 bf16 (48.8KB) + 64x16 f32 (4KB) ~ 118KB
// ---------------------------------------------------------------------------
__global__ __launch_bounds__(256) void xproj_fused(
    const __bf16* __restrict__ xib, const __bf16* __restrict__ Wx,
    const float* __restrict__ Wdt, const float* __restrict__ bdt,
    float* __restrict__ BC, unsigned* __restrict__ pdx)
{
    __shared__ __bf16 At[64*XSTR];
    __shared__ __bf16 Wls[48*XSTR];
    __shared__ float dtS[64*16];
    const int tid = threadIdx.x;
    const int lane = tid & 63, w = tid >> 6;
    const long r0 = (long)blockIdx.x*64;
    const int fr = lane & 15, fc = lane >> 4;

    // stage xi tile (zero-pad ghost rows)
    for (int idx = tid; idx < 64*64; idx += 256) {
        int r = idx >> 6, c8 = idx & 63;
        bf16x8 v = (r0 + r < ROWS) ? *(const bf16x8*)&xib[(r0+r)*512 + c8*8]
                                   : (bf16x8){};
        *(bf16x8*)&At[r*XSTR + c8*8] = v;
    }
    // stage Wx (48x512)
    for (int idx = tid; idx < 48*64; idx += 256) {
        int r = idx >> 6, c8 = idx & 63;
        *(bf16x8*)&Wls[r*XSTR + c8*8] = *(const bf16x8*)&Wx[r*512 + c8*8];
    }
    __syncthreads();

    // GEMM: wave w -> rows w*16..w*16+15, 48 cols
    f32x4 acc[3] = {};
    for (int k0 = 0; k0 < 512; k0 += 32) {
        bf16x8 a = *(const bf16x8*)&At[(w*16 + fr)*XSTR + k0 + fc*8];
        #pragma unroll
        for (int j = 0; j < 3; j++) {
            bf16x8 bv = *(const bf16x8*)&Wls[(j*16 + fr)*XSTR + k0 + fc*8];
            acc[j] = __builtin_amdgcn_mfma_f32_16x16x32_bf16(a, bv, acc[j], 0,0,0);
        }
    }
    // cols 0-15 -> dtS (LDS); cols 16-47 -> BC (global)
    #pragma unroll
    for (int rr = 0; rr < 4; rr++) {
        int lrow = w*16 + fc*4 + rr;
        long grow = r0 + lrow;
        dtS[lrow*16 + fr] = acc[0][rr];
        if (grow < ROWS) {
            BC[grow*32 + fr]      = acc[1][rr];
            BC[grow*32 + 16 + fr] = acc[2][rr];
        }
    }
    __syncthreads();

    // delta + pack: thread handles d = tid and tid+256, all 64 rows
    #pragma unroll
    for (int rep = 0; rep < 2; rep++) {
        const int d = tid + rep*256;
        f32x4 wa0 = *(const f32x4*)(Wdt + d*16);
        f32x4 wa1 = *(const f32x4*)(Wdt + d*16 + 4);
        f32x4 wa2 = *(const f32x4*)(Wdt + d*16 + 8);
        f32x4 wa3 = *(const f32x4*)(Wdt + d*16 + 12);
        const float bia = bdt[d];
        for (int r = 0; r < 64; r++) {
            long grow = r0 + r;
            if (grow >= ROWS) break;
            const float* dt = &dtS[r*16];
            float s = bia;
            #pragma unroll
            for (int e = 0; e < 4; e++)
                s += wa0[e]*dt[e] + wa1[e]*dt[4+e] + wa2[e]*dt[8+e] + wa3[e]*dt[12+e];
            float dl = (s > 20.f) ? s : log1pf(__expf(s));
            unsigned xb = __builtin_bit_cast(unsigned short, At[r*XSTR + d]);
            pdx[grow*512 + d] = (unsigned)bfbits(dl) | (xb << 16);
        }
    }
}

// ---------------------------------------------------------------------------
// Patch rearrange + LayerNorm(256) + skip add -> xxb; one wave per row.
// ---------------------------------------------------------------------------
__global__ __launch_bounds__(256) void rearrange_ln_cls(
    const __bf16* __restrict__ e_buf, const float* __restrict__ x,
    const float* __restrict__ cls_w, const float* __restrict__ cls_b,
    const float* __restrict__ ln_g, const float* __restrict__ ln_b,
    const float* __restrict__ skip, __bf16* __restrict__ xxb)
{
    const int wv = threadIdx.x >> 6, lane = threadIdx.x & 63;
    const int qg = blockIdx.x*4 + wv;
    if (qg >= ROWS) return;
    const int b = qg / L_TOT, q = qg % L_TOT;
    const long obase = (long)qg*256;

    if (q == 0) {
        const float* xr = x + (long)b*1025*512;
        #pragma unroll
        for (int i = 0; i < 4; i++) {
            int c = lane + i*64;
            float acc = cls_b[c];
            const float4* wr = (const float4*)(cls_w + (long)c*512);
            #pragma unroll 8
            for (int m4 = 0; m4 < 128; m4++) {
                float4 wv4 = wr[m4];
                float4 xv4 = *(const float4*)&xr[m4*4];
                acc += wv4.x*xv4.x + wv4.y*xv4.y + wv4.z*xv4.z + wv4.w*xv4.w;
            }
            xxb[obase + c] = (__bf16)(acc + skip[obase + c]);
        }
        return;
    }
    const int t  = (q-1) >> 10;
    const int p  = (q-1) & 1023;
    const int h  = p >> 6;
    const int a  = (p >> 5) & 1;
    const int w_ = (p >> 1) & 15;
    const int bb = p & 1;
    const long tok = (long)b*1024 + t*256 + h*16 + w_;
    const __bf16* src = e_buf + tok*1024 + a*512 + bb*256 + lane*4;
    float v[4];
    {
        ushort2 u0 = *(const ushort2*)src;
        ushort2 u1 = *(const ushort2*)(src+2);
        v[0] = (float)__builtin_bit_cast(__bf16, u0.x);
        v[1] = (float)__builtin_bit_cast(__bf16, u0.y);
        v[2] = (float)__builtin_bit_cast(__bf16, u1.x);
        v[3] = (float)__builtin_bit_cast(__bf16, u1.y);
    }
    float s = v[0]+v[1]+v[2]+v[3];
    float s2 = v[0]*v[0]+v[1]*v[1]+v[2]*v[2]+v[3]*v[3];
    #pragma unroll
    for (int o = 32; o > 0; o >>= 1) { s += __shfl_xor(s, o); s2 += __shfl_xor(s2, o); }
    float mu = s * (1.f/256.f);
    float rs = rsqrtf(s2*(1.f/256.f) - mu*mu + 1e-5f);
    const int c0 = lane*4;
    float4 sk = *(const float4*)&skip[obase + c0];
    float skv[4] = {sk.x, sk.y, sk.z, sk.w};
    __bf16 ov[4];
    #pragma unroll
    for (int i = 0; i < 4; i++)
        ov[i] = (__bf16)((v[i] - mu)*rs*ln_g[c0+i] + ln_b[c0+i] + skv[i]);
    *(ushort2*)&xxb[obase + c0]     = make_ushort2(
        __builtin_bit_cast(unsigned short, ov[0]),
        __builtin_bit_cast(unsigned short, ov[1]));
    *(ushort2*)&xxb[obase + c0 + 2] = make_ushort2(
        __builtin_bit_cast(unsigned short, ov[2]),
        __builtin_bit_cast(unsigned short, ov[3]));
}

// ---------------------------------------------------------------------------
// Depthwise causal conv (k=4)+SiLU on x-half only; thread = 8 chans x 8 rows
// ---------------------------------------------------------------------------
__global__ __launch_bounds__(256) void conv_silu(
    const __bf16* __restrict__ xhb, const float* __restrict__ cw,
    const float* __restrict__ cb, __bf16* __restrict__ xib)
{
    const int tid = threadIdx.x;
    const int c = tid & 63;
    const long r0 = ((long)blockIdx.x*4 + (tid >> 6))*8;
    if (r0 >= ROWS) return;
    const int d0 = c*8;
    float wreg[4][8], breg[8];
    #pragma unroll
    for (int e = 0; e < 8; e++) {
        breg[e] = cb[d0+e];
        #pragma unroll
        for (int k = 0; k < 4; k++) wreg[k][e] = cw[(d0+e)*4 + k];
    }
    bf16x8 win[4];
    #pragma unroll
    for (int j = 0; j < 3; j++) {
        long rr = r0 - 3 + j;
        win[j] = (rr >= 0) ? *(const bf16x8*)&xhb[rr*512 + d0] : (bf16x8){};
    }
    #pragma unroll
    for (int rr = 0; rr < 8; rr++) {
        long rl = r0 + rr;
        if (rl >= ROWS) break;
        win[3] = *(const bf16x8*)&xhb[rl*512 + d0];
        int l = (int)(rl % L_TOT);
        float acc[8];
        #pragma unroll
        for (int e = 0; e < 8; e++) acc[e] = breg[e];
        #pragma unroll
        for (int k = 0; k < 4; k++) {
            if (l + k - 3 >= 0) {
                #pragma unroll
                for (int e = 0; e < 8; e++)
                    acc[e] += wreg[k][e]*(float)win[k][e];
            }
        }
        bf16x8 o;
        #pragma unroll
        for (int e = 0; e < 8; e++) o[e] = (__bf16)siluf_(acc[e]);
        *(bf16x8*)&xib[rl*512 + d0] = o;
        win[0] = win[1]; win[1] = win[2]; win[2] = win[3];
    }
}

// ---------------------------------------------------------------------------
// Segmented scan, LDS-staged. Block = (seg, b, 64-d group); 256 thr = 64d x 4ng
// ---------------------------------------------------------------------------
__global__ __launch_bounds__(256) void scan_p1(
    const unsigned* __restrict__ pdx,
    const float* __restrict__ BC, const float* __restrict__ A_log,
    float* __restrict__ segH, float* __restrict__ segP)
{
    __shared__ unsigned pdxS[SEGLEN*64];
    __shared__ float bS[SEGLEN*16];
    const int blk = blockIdx.x;
    const int seg = blk >> 4;
    const int b   = (blk >> 3) & 1;
    const int dbase = (blk & 7)*64;
    const int tid = threadIdx.x;
    const int l0 = seg*SEGLEN;
    const int nl = min(l0 + SEGLEN, L_TOT) - l0;
    const int nlc = nl > 0 ? nl : 0;

    for (int cc = tid; cc < nlc*16; cc += 256) {
        int l = cc >> 4, qq = cc & 15;
        *(uint4*)&pdxS[l*64 + qq*4] =
            *(const uint4*)&pdx[((long)b*L_TOT + l0 + l)*512 + dbase + qq*4];
    }
    for (int cc = tid; cc < nlc*4; cc += 256) {
        int l = cc >> 2, qq = cc & 3;
        *(f32x4*)&bS[l*16 + qq*4] =
            *(const f32x4*)&BC[((long)b*L_TOT + l0 + l)*32 + qq*4];
    }
    __syncthreads();

    const int dl_ = tid >> 2;
    const int d = dbase + dl_;
    const int ng = tid & 3;
    f32x4 Al = *(const f32x4*)(A_log + d*16 + ng*4);
    float Ar[4] = {-__expf(Al[0]), -__expf(Al[1]), -__expf(Al[2]), -__expf(Al[3])};
    float h[4] = {0,0,0,0};
    float P[4] = {1,1,1,1};
    for (int l = 0; l < nlc; l++) {
        unsigned v = pdxS[l*64 + dl_];
        float dl = __uint_as_float(v << 16);
        float xv = __uint_as_float(v & 0xffff0000u);
        f32x4 Bv = *(const f32x4*)&bS[l*16 + ng*4];
        float dx = dl*xv;
        #pragma unroll
        for (int n = 0; n < 4; n++) {
            float E = __expf(dl*Ar[n]);
            h[n] = h[n]*E + dx*Bv[n];
            P[n] *= E;
        }
    }
    long off = ((long)(seg*2 + b)*512 + d)*16 + ng*4;
    *(f32x4*)&segH[off] = f32x4{h[0],h[1],h[2],h[3]};
    *(f32x4*)&segP[off] = f32x4{P[0],P[1],P[2],P[3]};
}

__global__ __launch_bounds__(256) void scan_p2(
    float* __restrict__ segH, const float* __restrict__ segP)
{
    const int idx = blockIdx.x*256 + threadIdx.x;   // 16384
    float carry = 0.f;
    for (int s0 = 0; s0 < NSEG; s0 += 8) {
        float hh[8], pp[8];
        #pragma unroll
        for (int j = 0; j < 8; j++) {
            long o = (long)(s0+j)*16384 + idx;
            hh[j] = segH[o]; pp[j] = segP[o];
        }
        #pragma unroll
        for (int j = 0; j < 8; j++) {
            long o = (long)(s0+j)*16384 + idx;
            segH[o] = carry;
            carry = pp[j]*carry + hh[j];
        }
    }
}

__global__ __launch_bounds__(256) void scan_p3(
    const unsigned* __restrict__ pdx,
    const float* __restrict__ BC, const float* __restrict__ A_log,
    const float* __restrict__ segH, const float* __restrict__ Dp,
    const __bf16* __restrict__ zsb, __bf16* __restrict__ yb)
{
    __shared__ unsigned pdxS[SEGLEN*64];
    __shared__ float bcS[SEGLEN*32];
    __shared__ __bf16 zS[SEGLEN*64];
    __shared__ __bf16 yS[SEGLEN*64];
    const int blk = blockIdx.x;
    const int seg = blk >> 4;
    const int b   = (blk >> 3) & 1;
    const int dbase = (blk & 7)*64;
    const int tid = threadIdx.x;
    const int l0 = seg*SEGLEN;
    const int nl = min(l0 + SEGLEN, L_TOT) - l0;
    const int nlc = nl > 0 ? nl : 0;
    if (nlc == 0) return;

    for (int cc = tid; cc < nlc*16; cc += 256) {
        int l = cc >> 4, qq = cc & 15;
        *(uint4*)&pdxS[l*64 + qq*4] =
            *(const uint4*)&pdx[((long)b*L_TOT + l0 + l)*512 + dbase + qq*4];
    }
    for (int cc = tid; cc < nlc*8; cc += 256) {
        int l = cc >> 3, qq = cc & 7;
        *(f32x4*)&bcS[l*32 + qq*4] =
            *(const f32x4*)&BC[((long)b*L_TOT + l0 + l)*32 + qq*4];
    }
    for (int cc = tid; cc < nlc*8; cc += 256) {
        int l = cc >> 3, qq = cc & 7;
        *(bf16x8*)&zS[l*64 + qq*8] =
            *(const bf16x8*)&zsb[((long)b*L_TOT + l0 + l)*512 + dbase + qq*8];
    }
    __syncthreads();

    const int dl_ = tid >> 2;
    const int d = dbase + dl_;
    const int ng = tid & 3;
    f32x4 Al = *(const f32x4*)(A_log + d*16 + ng*4);
    float Ar[4] = {-__expf(Al[0]), -__expf(Al[1]), -__expf(Al[2]), -__expf(Al[3])};
    long off = ((long)(seg*2 + b)*512 + d)*16 + ng*4;
    f32x4 h4 = *(const f32x4*)&segH[off];
    float h[4] = {h4[0], h4[1], h4[2], h4[3]};
    const float Dd = Dp[d];
    for (int l = 0; l < nlc; l++) {
        unsigned v = pdxS[l*64 + dl_];
        float dl = __uint_as_float(v << 16);
        float xv = __uint_as_float(v & 0xffff0000u);
        f32x4 Bv = *(const f32x4*)&bcS[l*32 + ng*4];
        f32x4 Cv = *(const f32x4*)&bcS[l*32 + 16 + ng*4];
        float dx = dl*xv;
        float y = 0.f;
        #pragma unroll
        for (int n = 0; n < 4; n++) {
            float E = __expf(dl*Ar[n]);
            h[n] = h[n]*E + dx*Bv[n];
            y += h[n]*Cv[n];
        }
        y += __shfl_xor(y, 1);
        y += __shfl_xor(y, 2);
        if (ng == 0) {
            float z = (float)zS[l*64 + dl_];
            yS[l*64 + dl_] = (__bf16)((y + xv*Dd)*z);
        }
    }
    __syncthreads();
    for (int cc = tid; cc < nlc*8; cc += 256) {
        int l = cc >> 3, qq = cc & 7;
        *(bf16x8*)&yb[((long)b*L_TOT + l0 + l)*512 + dbase + qq*8] =
            *(bf16x8*)&yS[l*64 + qq*8];
    }
}

// ---------------------------------------------------------------------------
// BatchNorm over rows (bf16 input)
// ---------------------------------------------------------------------------
__global__ void zero_stats(float* __restrict__ stats) { stats[threadIdx.x] = 0.f; }

__global__ __launch_bounds__(256) void bn_reduce(
    const __bf16* __restrict__ xxb, float* __restrict__ stats)
{
    const int c = threadIdx.x;
    float s = 0.f, s2 = 0.f;
    for (int r = blockIdx.x; r < ROWS; r += gridDim.x) {
        float v = (float)xxb[(long)r*256 + c];
        s += v; s2 += v*v;
    }
    atomicAdd(&stats[c], s);
    atomicAdd(&stats[256 + c], s2);
}

__global__ __launch_bounds__(256) void bn_apply(
    const __bf16* __restrict__ xxb, const float* __restrict__ stats,
    const float* __restrict__ g, const float* __restrict__ bta,
    float* __restrict__ out)
{
    long idx = (long)blockIdx.x*256 + threadIdx.x;
    if (idx == 0) out[(long)ROWS*256] = 1024.0f;
    if (idx >= (long)ROWS*256) return;
    int c = (int)(idx & 255);
    float mu = stats[c] * (1.f/ROWS);
    float var = stats[256 + c] * (1.f/ROWS) - mu*mu;
    out[idx] = ((float)xxb[idx] - mu)*rsqrtf(var + 1e-5f)*g[c] + bta[c];
}

// ---------------------------------------------------------------------------
extern "C" void kernel_launch(void* const* d_in, const int* in_sizes, int n_in,
                              void* d_out, int out_size, void* d_ws, size_t ws_size,
                              hipStream_t stream)
{
    const float* x        = (const float*)d_in[0];
    const float* skip     = (const float*)d_in[1];
    const float* exp_w    = (const float*)d_in[2];
    const float* ln_g     = (const float*)d_in[3];
    const float* ln_b     = (const float*)d_in[4];
    const float* cls_w    = (const float*)d_in[5];
    const float* cls_b    = (const float*)d_in[6];
    const float* in_proj_w= (const float*)d_in[7];
    const float* conv_w   = (const float*)d_in[8];
    const float* conv_b   = (const float*)d_in[9];
    const float* xproj_w  = (const float*)d_in[10];
    const float* dt_w     = (const float*)d_in[11];
    const float* dt_b     = (const float*)d_in[12];
    const float* A_log    = (const float*)d_in[13];
    const float* Dp       = (const float*)d_in[14];
    const float* out_w    = (const float*)d_in[15];
    const float* bn_g     = (const float*)d_in[16];
    const float* bn_b     = (const float*)d_in[17];

    float* ws = (float*)d_ws;
    float* BC    = ws;                       //   262,208 f32
    float* segH  = BC + 262208;              // 2,097,152 f32
    float* segP  = segH + 2097152;           // 2,097,152 f32
    float* stats = segP + 2097152;           //       512 f32
    unsigned* pdx = (unsigned*)(stats + 512);// 4,195,328 u32
    __bf16* expWb = (__bf16*)(pdx + 4195328);//   524,288
    __bf16* inWb  = expWb + 524288;          //   524,288
    __bf16* outWb = inWb + 524288;           //   262,144
    __bf16* xpWb  = outWb + 262144;          //    49,152
    __bf16* xxb   = xpWb + 49152;            // 2,097,664
    __bf16* xhb   = xxb + 2097664;           // 4,195,328  (e_b alias pre-loop)
    __bf16* e_b   = xhb;
    __bf16* zsb   = xhb + 4195328;           // 4,195,328
    __bf16* xib   = zsb + 4195328;           // 4,195,328  (Axb alias pre-loop)
    __bf16* Axb   = xib;
    __bf16* yb    = xib + 4195328;           // 4,195,328
    float* out    = (float*)d_out;

    cvt4<<<(1359872/8 + 255)/256, 256, 0, stream>>>(
        exp_w, in_proj_w, out_w, xproj_w, expWb, inWb, outWb, xpWb);
    cvt_gather_x<<<(1048576/8)/256, 256, 0, stream>>>(x, Axb);

    gemm_bf16<<<dim3(16, 16), 256, 0, stream>>>(
        Axb, expWb, e_b, 2048, 1024, 512);
    rearrange_ln_cls<<<(ROWS + 3)/4, 256, 0, stream>>>(
        e_b, x, cls_w, cls_b, ln_g, ln_b, skip, xxb);

    for (int layer = 0; layer < 2; layer++) {
        gemm_inproj<<<dim3(8, 65), 256, 0, stream>>>(
            xxb, inWb + layer*262144, xhb, zsb, ROWS, 256);
        conv_silu<<<(ROWS + 31)/32, 256, 0, stream>>>(
            xhb, conv_w + layer*512*4, conv_b + layer*512, xib);
        xproj_fused<<<(ROWS + 63)/64, 256, 0, stream>>>(
            xib, xpWb + layer*24576, dt_w + layer*512*16, dt_b + layer*512,
            BC, pdx);
        scan_p1<<<NSEG*16, 256, 0, stream>>>(
            pdx, BC, A_log + layer*512*16, segH, segP);
        scan_p2<<<64, 256, 0, stream>>>(segH, segP);
        scan_p3<<<NSEG*16, 256, 0, stream>>>(
            pdx, BC, A_log + layer*512*16, segH, Dp + layer*512, zsb, yb);
        gemm_bf16<<<dim3(4, 65), 256, 0, stream>>>(
            yb, outWb + layer*131072, xxb, ROWS, 256, 512);
    }

    zero_stats<<<1, 512, 0, stream>>>(stats);
    bn_reduce<<<128, 256, 0, stream>>>(xxb, stats);
    bn_apply<<<((long)ROWS*256 + 255)/256 + 1, 256, 0, stream>>>(
        xxb, stats, bn_g, bn_b, out);
}

// Round 7
// 432.092 us; speedup vs baseline: 1.1544x; 1.1544x over previous
//
#include <hip/hip_runtime.h>
#include <hip/hip_bf16.h>
#include <math.h>

#define L_TOT 4097
#define BSZ 2
#define ROWS (BSZ*L_TOT)   // 8194
#define NSEG 128
#define SEGLEN 33          // 128*33 = 4224 >= 4097

typedef __bf16 bf16x8 __attribute__((ext_vector_type(8)));
typedef float  f32x4  __attribute__((ext_vector_type(4)));
#define ASTR 56            // LDS row stride (bf16) for BK=32 staging tiles
#define AST2 72            // LDS row stride (bf16) for BK=64 staging tiles

__device__ __forceinline__ float sigmoidf_(float v){ return 1.0f/(1.0f+__expf(-v)); }
__device__ __forceinline__ float siluf_(float v){ return v * sigmoidf_(v); }
__device__ __forceinline__ unsigned short bfbits(float f){
    __bf16 h = (__bf16)f;
    return __builtin_bit_cast(unsigned short, h);
}

// ---------------------------------------------------------------------------
// f32 -> bf16 weight conversion (4 tensors in one launch)
// ---------------------------------------------------------------------------
__global__ __launch_bounds__(256) void cvt4(
    const float* __restrict__ w0, const float* __restrict__ w1,
    const float* __restrict__ w2, const float* __restrict__ w3,
    __bf16* __restrict__ o0, __bf16* __restrict__ o1,
    __bf16* __restrict__ o2, __bf16* __restrict__ o3)
{
    long i = ((long)blockIdx.x*256 + threadIdx.x)*8;
    const float* src; __bf16* dst; long off;
    if (i < 524288)        { src = w0; dst = o0; off = i; }
    else if (i < 1048576)  { src = w1; dst = o1; off = i - 524288; }
    else if (i < 1310720)  { src = w2; dst = o2; off = i - 1048576; }
    else if (i < 1359872)  { src = w3; dst = o3; off = i - 1310720; }
    else return;
    float4 a = *(const float4*)(src+off), b = *(const float4*)(src+off+4);
    bf16x8 o;
    o[0]=(__bf16)a.x; o[1]=(__bf16)a.y; o[2]=(__bf16)a.z; o[3]=(__bf16)a.w;
    o[4]=(__bf16)b.x; o[5]=(__bf16)b.y; o[6]=(__bf16)b.z; o[7]=(__bf16)b.w;
    *(bf16x8*)(dst+off) = o;
}

__global__ __launch_bounds__(256) void cvt_gather_x(
    const float* __restrict__ x, __bf16* __restrict__ out)
{
    long i = ((long)blockIdx.x*256 + threadIdx.x)*8;
    if (i >= 2048L*512) return;
    int row = (int)(i >> 9), col = (int)(i & 511);
    long srow = row + (row >> 10) + 1;
    const float* src = x + srow*512 + col;
    float4 a = *(const float4*)src, b = *(const float4*)(src+4);
    bf16x8 o;
    o[0]=(__bf16)a.x; o[1]=(__bf16)a.y; o[2]=(__bf16)a.z; o[3]=(__bf16)a.w;
    o[4]=(__bf16)b.x; o[5]=(__bf16)b.y; o[6]=(__bf16)b.z; o[7]=(__bf16)b.w;
    *(bf16x8*)(out+i) = o;
}

// ---------------------------------------------------------------------------
// bf16 MFMA GEMM (BM=128,BN=64,BK=32): C2[M,N] = A[M,K]*W[N,K]^T, bf16 out
// ---------------------------------------------------------------------------
__global__ __launch_bounds__(256) void gemm_bf16(
    const __bf16* __restrict__ A, const __bf16* __restrict__ W,
    __bf16* __restrict__ C2, int M, int N, int K)
{
    __shared__ __bf16 Als[128*ASTR];
    __shared__ __bf16 Wls[64*ASTR];
    const int tid = threadIdx.x;
    const int lane = tid & 63, w = tid >> 6;
    const int n0 = blockIdx.x*64, m0 = blockIdx.y*128;

    f32x4 acc[2][4] = {};
    const int arow = tid >> 1, ahalf = tid & 1;
    const int wrow = tid >> 2, wseg = tid & 3;
    const int fr = lane & 15, fc = lane >> 4;

    for (int k0 = 0; k0 < K; k0 += 32) {
        bf16x8 av0 = {}, av1 = {};
        if (m0 + arow < M) {
            const __bf16* src = A + (long)(m0+arow)*K + k0 + ahalf*16;
            av0 = *(const bf16x8*)src;
            av1 = *(const bf16x8*)(src+8);
        }
        bf16x8 wv = *(const bf16x8*)(W + (long)(n0+wrow)*K + k0 + wseg*8);
        __syncthreads();
        *(bf16x8*)&Als[arow*ASTR + ahalf*16]     = av0;
        *(bf16x8*)&Als[arow*ASTR + ahalf*16 + 8] = av1;
        *(bf16x8*)&Wls[wrow*ASTR + wseg*8]       = wv;
        __syncthreads();

        bf16x8 a0 = *(const bf16x8*)&Als[(w*32 +      fr)*ASTR + fc*8];
        bf16x8 a1 = *(const bf16x8*)&Als[(w*32 + 16 + fr)*ASTR + fc*8];
        #pragma unroll
        for (int j = 0; j < 4; j++) {
            bf16x8 bv = *(const bf16x8*)&Wls[(j*16 + fr)*ASTR + fc*8];
            acc[0][j] = __builtin_amdgcn_mfma_f32_16x16x32_bf16(a0, bv, acc[0][j], 0,0,0);
            acc[1][j] = __builtin_amdgcn_mfma_f32_16x16x32_bf16(a1, bv, acc[1][j], 0,0,0);
        }
    }
    #pragma unroll
    for (int i = 0; i < 2; i++) {
        #pragma unroll
        for (int rr = 0; rr < 4; rr++) {
            int grow = m0 + w*32 + i*16 + fc*4 + rr;
            if (grow < M) {
                #pragma unroll
                for (int j = 0; j < 4; j++)
                    C2[(long)grow*N + n0 + j*16 + fr] = (__bf16)acc[i][j][rr];
            }
        }
    }
}

// ---------------------------------------------------------------------------
// in_proj GEMM (BM=128,BN=128,BK=64, N=1024 fixed):
//   col<512 -> xhb raw bf16 [ROWS,512];  col>=512 -> zsb = silu(v) [ROWS,512]
// ---------------------------------------------------------------------------
__global__ __launch_bounds__(256) void gemm_inproj(
    const __bf16* __restrict__ A, const __bf16* __restrict__ W,
    __bf16* __restrict__ xhb, __bf16* __restrict__ zsb, int M, int K)
{
    __shared__ __bf16 Als[128*AST2];
    __shared__ __bf16 Wls[128*AST2];
    const int tid = threadIdx.x;
    const int lane = tid & 63, w = tid >> 6;
    const int n0 = blockIdx.x*128, m0 = blockIdx.y*128;
    const int fr = lane & 15, fc = lane >> 4;
    const int row2 = tid >> 1, half = tid & 1;

    f32x4 acc[2][8] = {};

    for (int k0 = 0; k0 < K; k0 += 64) {
        bf16x8 av[4], wv[4];
        const bool aok = (m0 + row2) < M;
        const __bf16* asrc = A + (long)(m0+row2)*K + k0 + half*32;
        const __bf16* wsrc = W + (long)(n0+row2)*K + k0 + half*32;
        #pragma unroll
        for (int e = 0; e < 4; e++) {
            av[e] = aok ? *(const bf16x8*)(asrc + e*8) : (bf16x8){};
            wv[e] = *(const bf16x8*)(wsrc + e*8);
        }
        __syncthreads();
        #pragma unroll
        for (int e = 0; e < 4; e++) {
            *(bf16x8*)&Als[row2*AST2 + half*32 + e*8] = av[e];
            *(bf16x8*)&Wls[row2*AST2 + half*32 + e*8] = wv[e];
        }
        __syncthreads();
        #pragma unroll
        for (int s = 0; s < 2; s++) {
            bf16x8 a0 = *(const bf16x8*)&Als[(w*32 +      fr)*AST2 + s*32 + fc*8];
            bf16x8 a1 = *(const bf16x8*)&Als[(w*32 + 16 + fr)*AST2 + s*32 + fc*8];
            #pragma unroll
            for (int j = 0; j < 8; j++) {
                bf16x8 bv = *(const bf16x8*)&Wls[(j*16 + fr)*AST2 + s*32 + fc*8];
                acc[0][j] = __builtin_amdgcn_mfma_f32_16x16x32_bf16(a0, bv, acc[0][j], 0,0,0);
                acc[1][j] = __builtin_amdgcn_mfma_f32_16x16x32_bf16(a1, bv, acc[1][j], 0,0,0);
            }
        }
    }
    const bool xhalf = (n0 < 512);
    const int cbase = xhalf ? n0 : (n0 - 512);
    #pragma unroll
    for (int i = 0; i < 2; i++) {
        #pragma unroll
        for (int rr = 0; rr < 4; rr++) {
            int grow = m0 + w*32 + i*16 + fc*4 + rr;
            if (grow < M) {
                if (xhalf) {
                    #pragma unroll
                    for (int j = 0; j < 8; j++)
                        xhb[(long)grow*512 + cbase + j*16 + fr] = (__bf16)acc[i][j][rr];
                } else {
                    #pragma unroll
                    for (int j = 0; j < 8; j++)
                        zsb[(long)grow*512 + cbase + j*16 + fr] = (__bf16)siluf_(acc[i][j][rr]);
                }
            }
        }
    }
}

// ---------------------------------------------------------------------------
// dbc GEMM: [dt16 | BC] = xib[M,512] @ Wx[48,512]^T.  BM=64, 128 threads.
// dt16[ROWS,16] f32 (cols 0-15), BC[ROWS,32] f32 (cols 16-47).
// ---------------------------------------------------------------------------
__global__ __launch_bounds__(128) void gemm_dbc(
    const __bf16* __restrict__ A, const __bf16* __restrict__ W,
    float* __restrict__ dt16, float* __restrict__ BC, int M)
{
    __shared__ __bf16 Als[64*ASTR];
    __shared__ __bf16 Wls[48*ASTR];
    const int tid = threadIdx.x;
    const int lane = tid & 63, w = tid >> 6;
    const int m0 = blockIdx.x*64;
    f32x4 acc[2][3] = {};

    const int arow = tid >> 1, ahalf = tid & 1;
    const int fr = lane & 15, fc = lane >> 4;

    for (int k0 = 0; k0 < 512; k0 += 32) {
        bf16x8 av0 = {}, av1 = {};
        if (m0 + arow < M) {
            const __bf16* src = A + (long)(m0+arow)*512 + k0 + ahalf*16;
            av0 = *(const bf16x8*)src;
            av1 = *(const bf16x8*)(src+8);
        }
        bf16x8 wv0 = {}, wv1 = {};
        if (tid < 96) {
            const __bf16* src = W + (long)(tid>>1)*512 + k0 + (tid&1)*16;
            wv0 = *(const bf16x8*)src;
            wv1 = *(const bf16x8*)(src+8);
        }
        __syncthreads();
        *(bf16x8*)&Als[arow*ASTR + ahalf*16]     = av0;
        *(bf16x8*)&Als[arow*ASTR + ahalf*16 + 8] = av1;
        if (tid < 96) {
            *(bf16x8*)&Wls[(tid>>1)*ASTR + (tid&1)*16]     = wv0;
            *(bf16x8*)&Wls[(tid>>1)*ASTR + (tid&1)*16 + 8] = wv1;
        }
        __syncthreads();

        bf16x8 a0 = *(const bf16x8*)&Als[(w*32 +      fr)*ASTR + fc*8];
        bf16x8 a1 = *(const bf16x8*)&Als[(w*32 + 16 + fr)*ASTR + fc*8];
        #pragma unroll
        for (int j = 0; j < 3; j++) {
            bf16x8 bv = *(const bf16x8*)&Wls[(j*16 + fr)*ASTR + fc*8];
            acc[0][j] = __builtin_amdgcn_mfma_f32_16x16x32_bf16(a0, bv, acc[0][j], 0,0,0);
            acc[1][j] = __builtin_amdgcn_mfma_f32_16x16x32_bf16(a1, bv, acc[1][j], 0,0,0);
        }
    }
    #pragma unroll
    for (int i = 0; i < 2; i++) {
        #pragma unroll
        for (int rr = 0; rr < 4; rr++) {
            long grow = m0 + w*32 + i*16 + fc*4 + rr;
            if (grow < M) {
                dt16[grow*16 + fr]    = acc[i][0][rr];
                BC[grow*32 + fr]      = acc[i][1][rr];
                BC[grow*32 + 16 + fr] = acc[i][2][rr];
            }
        }
    }
}

// ---------------------------------------------------------------------------
// delta: softplus(dt16 @ Wdt^T + bdt); pack (delta, xi) bf16 pair -> pdx u32.
// Block = 8 rows; dt16 rows staged in LDS.
// ---------------------------------------------------------------------------
__global__ __launch_bounds__(256) void delta_k(
    const float* __restrict__ dt16, const float* __restrict__ Wdt,
    const float* __restrict__ bdt, const __bf16* __restrict__ xib,
    unsigned* __restrict__ pdx)
{
    __shared__ float dtS[8*16];
    const int tid = threadIdx.x;
    const long r0 = (long)blockIdx.x*8;
    if (tid < 32) {
        long idx = r0*16 + tid*4;
        f32x4 v = (idx < (long)ROWS*16) ? *(const f32x4*)&dt16[idx] : (f32x4){};
        *(f32x4*)&dtS[tid*4] = v;
    }
    const int d0 = tid, d1 = tid + 256;
    f32x4 wa[4], wb[4];
    #pragma unroll
    for (int q = 0; q < 4; q++) {
        wa[q] = *(const f32x4*)(Wdt + d0*16 + q*4);
        wb[q] = *(const f32x4*)(Wdt + d1*16 + q*4);
    }
    const float b0 = bdt[d0], b1 = bdt[d1];
    __syncthreads();
    #pragma unroll
    for (int rr = 0; rr < 8; rr++) {
        long row = r0 + rr;
        if (row >= ROWS) return;
        const float* dt = &dtS[rr*16];
        float s0 = b0, s1 = b1;
        #pragma unroll
        for (int e = 0; e < 4; e++) {
            s0 += wa[0][e]*dt[e] + wa[1][e]*dt[4+e] + wa[2][e]*dt[8+e] + wa[3][e]*dt[12+e];
            s1 += wb[0][e]*dt[e] + wb[1][e]*dt[4+e] + wb[2][e]*dt[8+e] + wb[3][e]*dt[12+e];
        }
        float dl0 = (s0 > 20.f) ? s0 : log1pf(__expf(s0));
        float dl1 = (s1 > 20.f) ? s1 : log1pf(__expf(s1));
        unsigned x0 = __builtin_bit_cast(unsigned short, xib[row*512 + d0]);
        unsigned x1 = __builtin_bit_cast(unsigned short, xib[row*512 + d1]);
        pdx[row*512 + d0] = (unsigned)bfbits(dl0) | (x0 << 16);
        pdx[row*512 + d1] = (unsigned)bfbits(dl1) | (x1 << 16);
    }
}

// ---------------------------------------------------------------------------
// Patch rearrange + LayerNorm(256) + skip add -> xxb; one wave per row.
// ---------------------------------------------------------------------------
__global__ __launch_bounds__(256) void rearrange_ln_cls(
    const __bf16* __restrict__ e_buf, const float* __restrict__ x,
    const float* __restrict__ cls_w, const float* __restrict__ cls_b,
    const float* __restrict__ ln_g, const float* __restrict__ ln_b,
    const float* __restrict__ skip, __bf16* __restrict__ xxb)
{
    const int wv = threadIdx.x >> 6, lane = threadIdx.x & 63;
    const int qg = blockIdx.x*4 + wv;
    if (qg >= ROWS) return;
    const int b = qg / L_TOT, q = qg % L_TOT;
    const long obase = (long)qg*256;

    if (q == 0) {
        const float* xr = x + (long)b*1025*512;
        #pragma unroll
        for (int i = 0; i < 4; i++) {
            int c = lane + i*64;
            float acc = cls_b[c];
            const float4* wr = (const float4*)(cls_w + (long)c*512);
            #pragma unroll 8
            for (int m4 = 0; m4 < 128; m4++) {
                float4 wv4 = wr[m4];
                float4 xv4 = *(const float4*)&xr[m4*4];
                acc += wv4.x*xv4.x + wv4.y*xv4.y + wv4.z*xv4.z + wv4.w*xv4.w;
            }
            xxb[obase + c] = (__bf16)(acc + skip[obase + c]);
        }
        return;
    }
    const int t  = (q-1) >> 10;
    const int p  = (q-1) & 1023;
    const int h  = p >> 6;
    const int a  = (p >> 5) & 1;
    const int w_ = (p >> 1) & 15;
    const int bb = p & 1;
    const long tok = (long)b*1024 + t*256 + h*16 + w_;
    const __bf16* src = e_buf + tok*1024 + a*512 + bb*256 + lane*4;
    float v[4];
    {
        ushort2 u0 = *(const ushort2*)src;
        ushort2 u1 = *(const ushort2*)(src+2);
        v[0] = (float)__builtin_bit_cast(__bf16, u0.x);
        v[1] = (float)__builtin_bit_cast(__bf16, u0.y);
        v[2] = (float)__builtin_bit_cast(__bf16, u1.x);
        v[3] = (float)__builtin_bit_cast(__bf16, u1.y);
    }
    float s = v[0]+v[1]+v[2]+v[3];
    float s2 = v[0]*v[0]+v[1]*v[1]+v[2]*v[2]+v[3]*v[3];
    #pragma unroll
    for (int o = 32; o > 0; o >>= 1) { s += __shfl_xor(s, o); s2 += __shfl_xor(s2, o); }
    float mu = s * (1.f/256.f);
    float rs = rsqrtf(s2*(1.f/256.f) - mu*mu + 1e-5f);
    const int c0 = lane*4;
    float4 sk = *(const float4*)&skip[obase + c0];
    float skv[4] = {sk.x, sk.y, sk.z, sk.w};
    __bf16 ov[4];
    #pragma unroll
    for (int i = 0; i < 4; i++)
        ov[i] = (__bf16)((v[i] - mu)*rs*ln_g[c0+i] + ln_b[c0+i] + skv[i]);
    *(ushort2*)&xxb[obase + c0]     = make_ushort2(
        __builtin_bit_cast(unsigned short, ov[0]),
        __builtin_bit_cast(unsigned short, ov[1]));
    *(ushort2*)&xxb[obase + c0 + 2] = make_ushort2(
        __builtin_bit_cast(unsigned short, ov[2]),
        __builtin_bit_cast(unsigned short, ov[3]));
}

// ---------------------------------------------------------------------------
// Depthwise causal conv (k=4)+SiLU on x-half only; thread = 8 chans x 8 rows
// ---------------------------------------------------------------------------
__global__ __launch_bounds__(256) void conv_silu(
    const __bf16* __restrict__ xhb, const float* __restrict__ cw,
    const float* __restrict__ cb, __bf16* __restrict__ xib)
{
    const int tid = threadIdx.x;
    const int c = tid & 63;
    const long r0 = ((long)blockIdx.x*4 + (tid >> 6))*8;
    if (r0 >= ROWS) return;
    const int d0 = c*8;
    float wreg[4][8], breg[8];
    #pragma unroll
    for (int e = 0; e < 8; e++) {
        breg[e] = cb[d0+e];
        #pragma unroll
        for (int k = 0; k < 4; k++) wreg[k][e] = cw[(d0+e)*4 + k];
    }
    bf16x8 win[4];
    #pragma unroll
    for (int j = 0; j < 3; j++) {
        long rr = r0 - 3 + j;
        win[j] = (rr >= 0) ? *(const bf16x8*)&xhb[rr*512 + d0] : (bf16x8){};
    }
    #pragma unroll
    for (int rr = 0; rr < 8; rr++) {
        long rl = r0 + rr;
        if (rl >= ROWS) break;
        win[3] = *(const bf16x8*)&xhb[rl*512 + d0];
        int l = (int)(rl % L_TOT);
        float acc[8];
        #pragma unroll
        for (int e = 0; e < 8; e++) acc[e] = breg[e];
        #pragma unroll
        for (int k = 0; k < 4; k++) {
            if (l + k - 3 >= 0) {
                #pragma unroll
                for (int e = 0; e < 8; e++)
                    acc[e] += wreg[k][e]*(float)win[k][e];
            }
        }
        bf16x8 o;
        #pragma unroll
        for (int e = 0; e < 8; e++) o[e] = (__bf16)siluf_(acc[e]);
        *(bf16x8*)&xib[rl*512 + d0] = o;
        win[0] = win[1]; win[1] = win[2]; win[2] = win[3];
    }
}

// ---------------------------------------------------------------------------
// Segmented scan, LDS-staged. Block = (seg, b, 64-d group); 256 thr = 64d x 4ng
// ---------------------------------------------------------------------------
__global__ __launch_bounds__(256) void scan_p1(
    const unsigned* __restrict__ pdx,
    const float* __restrict__ BC, const float* __restrict__ A_log,
    float* __restrict__ segH, float* __restrict__ segP)
{
    __shared__ unsigned pdxS[SEGLEN*64];
    __shared__ float bS[SEGLEN*16];
    const int blk = blockIdx.x;
    const int seg = blk >> 4;
    const int b   = (blk >> 3) & 1;
    const int dbase = (blk & 7)*64;
    const int tid = threadIdx.x;
    const int l0 = seg*SEGLEN;
    const int nl = min(l0 + SEGLEN, L_TOT) - l0;
    const int nlc = nl > 0 ? nl : 0;

    for (int cc = tid; cc < nlc*16; cc += 256) {
        int l = cc >> 4, qq = cc & 15;
        *(uint4*)&pdxS[l*64 + qq*4] =
            *(const uint4*)&pdx[((long)b*L_TOT + l0 + l)*512 + dbase + qq*4];
    }
    for (int cc = tid; cc < nlc*4; cc += 256) {
        int l = cc >> 2, qq = cc & 3;
        *(f32x4*)&bS[l*16 + qq*4] =
            *(const f32x4*)&BC[((long)b*L_TOT + l0 + l)*32 + qq*4];
    }
    __syncthreads();

    const int dl_ = tid >> 2;
    const int d = dbase + dl_;
    const int ng = tid & 3;
    f32x4 Al = *(const f32x4*)(A_log + d*16 + ng*4);
    float Ar[4] = {-__expf(Al[0]), -__expf(Al[1]), -__expf(Al[2]), -__expf(Al[3])};
    float h[4] = {0,0,0,0};
    float P[4] = {1,1,1,1};
    for (int l = 0; l < nlc; l++) {
        unsigned v = pdxS[l*64 + dl_];
        float dl = __uint_as_float(v << 16);
        float xv = __uint_as_float(v & 0xffff0000u);
        f32x4 Bv = *(const f32x4*)&bS[l*16 + ng*4];
        float dx = dl*xv;
        #pragma unroll
        for (int n = 0; n < 4; n++) {
            float E = __expf(dl*Ar[n]);
            h[n] = h[n]*E + dx*Bv[n];
            P[n] *= E;
        }
    }
    long off = ((long)(seg*2 + b)*512 + d)*16 + ng*4;
    *(f32x4*)&segH[off] = f32x4{h[0],h[1],h[2],h[3]};
    *(f32x4*)&segP[off] = f32x4{P[0],P[1],P[2],P[3]};
}

__global__ __launch_bounds__(256) void scan_p2(
    float* __restrict__ segH, const float* __restrict__ segP)
{
    const int idx = blockIdx.x*256 + threadIdx.x;   // 16384
    float carry = 0.f;
    for (int s0 = 0; s0 < NSEG; s0 += 8) {
        float hh[8], pp[8];
        #pragma unroll
        for (int j = 0; j < 8; j++) {
            long o = (long)(s0+j)*16384 + idx;
            hh[j] = segH[o]; pp[j] = segP[o];
        }
        #pragma unroll
        for (int j = 0; j < 8; j++) {
            long o = (long)(s0+j)*16384 + idx;
            segH[o] = carry;
            carry = pp[j]*carry + hh[j];
        }
    }
}

__global__ __launch_bounds__(256) void scan_p3(
    const unsigned* __restrict__ pdx,
    const float* __restrict__ BC, const float* __restrict__ A_log,
    const float* __restrict__ segH, const float* __restrict__ Dp,
    const __bf16* __restrict__ zsb, __bf16* __restrict__ yb)
{
    __shared__ unsigned pdxS[SEGLEN*64];
    __shared__ float bcS[SEGLEN*32];
    __shared__ __bf16 zS[SEGLEN*64];
    __shared__ __bf16 yS[SEGLEN*64];
    const int blk = blockIdx.x;
    const int seg = blk >> 4;
    const int b   = (blk >> 3) & 1;
    const int dbase = (blk & 7)*64;
    const int tid = threadIdx.x;
    const int l0 = seg*SEGLEN;
    const int nl = min(l0 + SEGLEN, L_TOT) - l0;
    const int nlc = nl > 0 ? nl : 0;
    if (nlc == 0) return;

    for (int cc = tid; cc < nlc*16; cc += 256) {
        int l = cc >> 4, qq = cc & 15;
        *(uint4*)&pdxS[l*64 + qq*4] =
            *(const uint4*)&pdx[((long)b*L_TOT + l0 + l)*512 + dbase + qq*4];
    }
    for (int cc = tid; cc < nlc*8; cc += 256) {
        int l = cc >> 3, qq = cc & 7;
        *(f32x4*)&bcS[l*32 + qq*4] =
            *(const f32x4*)&BC[((long)b*L_TOT + l0 + l)*32 + qq*4];
    }
    for (int cc = tid; cc < nlc*8; cc += 256) {
        int l = cc >> 3, qq = cc & 7;
        *(bf16x8*)&zS[l*64 + qq*8] =
            *(const bf16x8*)&zsb[((long)b*L_TOT + l0 + l)*512 + dbase + qq*8];
    }
    __syncthreads();

    const int dl_ = tid >> 2;
    const int d = dbase + dl_;
    const int ng = tid & 3;
    f32x4 Al = *(const f32x4*)(A_log + d*16 + ng*4);
    float Ar[4] = {-__expf(Al[0]), -__expf(Al[1]), -__expf(Al[2]), -__expf(Al[3])};
    long off = ((long)(seg*2 + b)*512 + d)*16 + ng*4;
    f32x4 h4 = *(const f32x4*)&segH[off];
    float h[4] = {h4[0], h4[1], h4[2], h4[3]};
    const float Dd = Dp[d];
    for (int l = 0; l < nlc; l++) {
        unsigned v = pdxS[l*64 + dl_];
        float dl = __uint_as_float(v << 16);
        float xv = __uint_as_float(v & 0xffff0000u);
        f32x4 Bv = *(const f32x4*)&bcS[l*32 + ng*4];
        f32x4 Cv = *(const f32x4*)&bcS[l*32 + 16 + ng*4];
        float dx = dl*xv;
        float y = 0.f;
        #pragma unroll
        for (int n = 0; n < 4; n++) {
            float E = __expf(dl*Ar[n]);
            h[n] = h[n]*E + dx*Bv[n];
            y += h[n]*Cv[n];
        }
        y += __shfl_xor(y, 1);
        y += __shfl_xor(y, 2);
        if (ng == 0) {
            float z = (float)zS[l*64 + dl_];
            yS[l*64 + dl_] = (__bf16)((y + xv*Dd)*z);
        }
    }
    __syncthreads();
    for (int cc = tid; cc < nlc*8; cc += 256) {
        int l = cc >> 3, qq = cc & 7;
        *(bf16x8*)&yb[((long)b*L_TOT + l0 + l)*512 + dbase + qq*8] =
            *(bf16x8*)&yS[l*64 + qq*8];
    }
}

// ---------------------------------------------------------------------------
// BatchNorm over rows (bf16 input)
// ---------------------------------------------------------------------------
__global__ void zero_stats(float* __restrict__ stats) { stats[threadIdx.x] = 0.f; }

__global__ __launch_bounds__(256) void bn_reduce(
    const __bf16* __restrict__ xxb, float* __restrict__ stats)
{
    const int c = threadIdx.x;
    float s = 0.f, s2 = 0.f;
    for (int r = blockIdx.x; r < ROWS; r += gridDim.x) {
        float v = (float)xxb[(long)r*256 + c];
        s += v; s2 += v*v;
    }
    atomicAdd(&stats[c], s);
    atomicAdd(&stats[256 + c], s2);
}

__global__ __launch_bounds__(256) void bn_apply(
    const __bf16* __restrict__ xxb, const float* __restrict__ stats,
    const float* __restrict__ g, const float* __restrict__ bta,
    float* __restrict__ out)
{
    long idx = (long)blockIdx.x*256 + threadIdx.x;
    if (idx == 0) out[(long)ROWS*256] = 1024.0f;
    if (idx >= (long)ROWS*256) return;
    int c = (int)(idx & 255);
    float mu = stats[c] * (1.f/ROWS);
    float var = stats[256 + c] * (1.f/ROWS) - mu*mu;
    out[idx] = ((float)xxb[idx] - mu)*rsqrtf(var + 1e-5f)*g[c] + bta[c];
}

// ---------------------------------------------------------------------------
extern "C" void kernel_launch(void* const* d_in, const int* in_sizes, int n_in,
                              void* d_out, int out_size, void* d_ws, size_t ws_size,
                              hipStream_t stream)
{
    const float* x        = (const float*)d_in[0];
    const float* skip     = (const float*)d_in[1];
    const float* exp_w    = (const float*)d_in[2];
    const float* ln_g     = (const float*)d_in[3];
    const float* ln_b     = (const float*)d_in[4];
    const float* cls_w    = (const float*)d_in[5];
    const float* cls_b    = (const float*)d_in[6];
    const float* in_proj_w= (const float*)d_in[7];
    const float* conv_w   = (const float*)d_in[8];
    const float* conv_b   = (const float*)d_in[9];
    const float* xproj_w  = (const float*)d_in[10];
    const float* dt_w     = (const float*)d_in[11];
    const float* dt_b     = (const float*)d_in[12];
    const float* A_log    = (const float*)d_in[13];
    const float* Dp       = (const float*)d_in[14];
    const float* out_w    = (const float*)d_in[15];
    const float* bn_g     = (const float*)d_in[16];
    const float* bn_b     = (const float*)d_in[17];

    float* ws = (float*)d_ws;
    float* BC    = ws;                       //   262,208 f32
    float* dt16  = BC + 262208;              //   131,104 f32
    float* segH  = dt16 + 131104;            // 2,097,152 f32
    float* segP  = segH + 2097152;           // 2,097,152 f32
    float* stats = segP + 2097152;           //       512 f32
    unsigned* pdx = (unsigned*)(stats + 512);// 4,195,328 u32
    __bf16* expWb = (__bf16*)(pdx + 4195328);//   524,288
    __bf16* inWb  = expWb + 524288;          //   524,288
    __bf16* outWb = inWb + 524288;           //   262,144
    __bf16* xpWb  = outWb + 262144;          //    49,152
    __bf16* xxb   = xpWb + 49152;            // 2,097,664
    __bf16* xhb   = xxb + 2097664;           // 4,195,328  (e_b alias pre-loop)
    __bf16* e_b   = xhb;
    __bf16* zsb   = xhb + 4195328;           // 4,195,328
    __bf16* xib   = zsb + 4195328;           // 4,195,328  (Axb alias pre-loop)
    __bf16* Axb   = xib;
    __bf16* yb    = xib + 4195328;           // 4,195,328
    float* out    = (float*)d_out;

    cvt4<<<(1359872/8 + 255)/256, 256, 0, stream>>>(
        exp_w, in_proj_w, out_w, xproj_w, expWb, inWb, outWb, xpWb);
    cvt_gather_x<<<(1048576/8)/256, 256, 0, stream>>>(x, Axb);

    gemm_bf16<<<dim3(16, 16), 256, 0, stream>>>(
        Axb, expWb, e_b, 2048, 1024, 512);
    rearrange_ln_cls<<<(ROWS + 3)/4, 256, 0, stream>>>(
        e_b, x, cls_w, cls_b, ln_g, ln_b, skip, xxb);

    for (int layer = 0; layer < 2; layer++) {
        gemm_inproj<<<dim3(8, 65), 256, 0, stream>>>(
            xxb, inWb + layer*262144, xhb, zsb, ROWS, 256);
        conv_silu<<<(ROWS + 31)/32, 256, 0, stream>>>(
            xhb, conv_w + layer*512*4, conv_b + layer*512, xib);
        gemm_dbc<<<(ROWS + 63)/64, 128, 0, stream>>>(
            xib, xpWb + layer*24576, dt16, BC, ROWS);
        delta_k<<<(ROWS + 7)/8, 256, 0, stream>>>(
            dt16, dt_w + layer*512*16, dt_b + layer*512, xib, pdx);
        scan_p1<<<NSEG*16, 256, 0, stream>>>(
            pdx, BC, A_log + layer*512*16, segH, segP);
        scan_p2<<<64, 256, 0, stream>>>(segH, segP);
        scan_p3<<<NSEG*16, 256, 0, stream>>>(
            pdx, BC, A_log + layer*512*16, segH, Dp + layer*512, zsb, yb);
        gemm_bf16<<<dim3(4, 65), 256, 0, stream>>>(
            yb, outWb + layer*131072, xxb, ROWS, 256, 512);
    }

    zero_stats<<<1, 512, 0, stream>>>(stats);
    bn_reduce<<<128, 256, 0, stream>>>(xxb, stats);
    bn_apply<<<((long)ROWS*256 + 255)/256 + 1, 256, 0, stream>>>(
        xxb, stats, bn_g, bn_b, out);
}

// Round 8
// 392.026 us; speedup vs baseline: 1.2724x; 1.1022x over previous
//
#include <hip/hip_runtime.h>
#include <hip/hip_bf16.h>
#include <math.h>

#define L_TOT 4097
#define BSZ 2
#define ROWS (BSZ*L_TOT)   // 8194
#define NSEG 128
#define SEGLEN 33          // 128*33 = 4224 >= 4097

typedef __bf16 bf16x8 __attribute__((ext_vector_type(8)));
typedef float  f32x4  __attribute__((ext_vector_type(4)));
#define ASTR 56            // LDS row stride (bf16) for BK=32 staging tiles
#define AST2 72            // LDS row stride (bf16) for BK=64 staging tiles

__device__ __forceinline__ float sigmoidf_(float v){ return 1.0f/(1.0f+__expf(-v)); }
__device__ __forceinline__ float siluf_(float v){ return v * sigmoidf_(v); }
__device__ __forceinline__ unsigned short bfbits(float f){
    __bf16 h = (__bf16)f;
    return __builtin_bit_cast(unsigned short, h);
}

// ---------------------------------------------------------------------------
// f32 -> bf16 weight conversion (4 tensors in one launch)
// ---------------------------------------------------------------------------
__global__ __launch_bounds__(256) void cvt4(
    const float* __restrict__ w0, const float* __restrict__ w1,
    const float* __restrict__ w2, const float* __restrict__ w3,
    __bf16* __restrict__ o0, __bf16* __restrict__ o1,
    __bf16* __restrict__ o2, __bf16* __restrict__ o3)
{
    long i = ((long)blockIdx.x*256 + threadIdx.x)*8;
    const float* src; __bf16* dst; long off;
    if (i < 524288)        { src = w0; dst = o0; off = i; }
    else if (i < 1048576)  { src = w1; dst = o1; off = i - 524288; }
    else if (i < 1310720)  { src = w2; dst = o2; off = i - 1048576; }
    else if (i < 1359872)  { src = w3; dst = o3; off = i - 1310720; }
    else return;
    float4 a = *(const float4*)(src+off), b = *(const float4*)(src+off+4);
    bf16x8 o;
    o[0]=(__bf16)a.x; o[1]=(__bf16)a.y; o[2]=(__bf16)a.z; o[3]=(__bf16)a.w;
    o[4]=(__bf16)b.x; o[5]=(__bf16)b.y; o[6]=(__bf16)b.z; o[7]=(__bf16)b.w;
    *(bf16x8*)(dst+off) = o;
}

__global__ __launch_bounds__(256) void cvt_gather_x(
    const float* __restrict__ x, __bf16* __restrict__ out)
{
    long i = ((long)blockIdx.x*256 + threadIdx.x)*8;
    if (i >= 2048L*512) return;
    int row = (int)(i >> 9), col = (int)(i & 511);
    long srow = row + (row >> 10) + 1;
    const float* src = x + srow*512 + col;
    float4 a = *(const float4*)src, b = *(const float4*)(src+4);
    bf16x8 o;
    o[0]=(__bf16)a.x; o[1]=(__bf16)a.y; o[2]=(__bf16)a.z; o[3]=(__bf16)a.w;
    o[4]=(__bf16)b.x; o[5]=(__bf16)b.y; o[6]=(__bf16)b.z; o[7]=(__bf16)b.w;
    *(bf16x8*)(out+i) = o;
}

// ---------------------------------------------------------------------------
// bf16 MFMA GEMM (BM=128,BN=64,BK=32): C2[M,N] = A[M,K]*W[N,K]^T, bf16 out
// ---------------------------------------------------------------------------
__global__ __launch_bounds__(256) void gemm_bf16(
    const __bf16* __restrict__ A, const __bf16* __restrict__ W,
    __bf16* __restrict__ C2, int M, int N, int K)
{
    __shared__ __bf16 Als[128*ASTR];
    __shared__ __bf16 Wls[64*ASTR];
    const int tid = threadIdx.x;
    const int lane = tid & 63, w = tid >> 6;
    const int n0 = blockIdx.x*64, m0 = blockIdx.y*128;

    f32x4 acc[2][4] = {};
    const int arow = tid >> 1, ahalf = tid & 1;
    const int wrow = tid >> 2, wseg = tid & 3;
    const int fr = lane & 15, fc = lane >> 4;

    for (int k0 = 0; k0 < K; k0 += 32) {
        bf16x8 av0 = {}, av1 = {};
        if (m0 + arow < M) {
            const __bf16* src = A + (long)(m0+arow)*K + k0 + ahalf*16;
            av0 = *(const bf16x8*)src;
            av1 = *(const bf16x8*)(src+8);
        }
        bf16x8 wv = *(const bf16x8*)(W + (long)(n0+wrow)*K + k0 + wseg*8);
        __syncthreads();
        *(bf16x8*)&Als[arow*ASTR + ahalf*16]     = av0;
        *(bf16x8*)&Als[arow*ASTR + ahalf*16 + 8] = av1;
        *(bf16x8*)&Wls[wrow*ASTR + wseg*8]       = wv;
        __syncthreads();

        bf16x8 a0 = *(const bf16x8*)&Als[(w*32 +      fr)*ASTR + fc*8];
        bf16x8 a1 = *(const bf16x8*)&Als[(w*32 + 16 + fr)*ASTR + fc*8];
        #pragma unroll
        for (int j = 0; j < 4; j++) {
            bf16x8 bv = *(const bf16x8*)&Wls[(j*16 + fr)*ASTR + fc*8];
            acc[0][j] = __builtin_amdgcn_mfma_f32_16x16x32_bf16(a0, bv, acc[0][j], 0,0,0);
            acc[1][j] = __builtin_amdgcn_mfma_f32_16x16x32_bf16(a1, bv, acc[1][j], 0,0,0);
        }
    }
    #pragma unroll
    for (int i = 0; i < 2; i++) {
        #pragma unroll
        for (int rr = 0; rr < 4; rr++) {
            int grow = m0 + w*32 + i*16 + fc*4 + rr;
            if (grow < M) {
                #pragma unroll
                for (int j = 0; j < 4; j++)
                    C2[(long)grow*N + n0 + j*16 + fr] = (__bf16)acc[i][j][rr];
            }
        }
    }
}

// ---------------------------------------------------------------------------
// in_proj GEMM (BM=128,BN=128,BK=64, N=1024 fixed):
//   col<512 -> xhb raw bf16 [ROWS,512];  col>=512 -> zsb = silu(v) [ROWS,512]
// ---------------------------------------------------------------------------
__global__ __launch_bounds__(256) void gemm_inproj(
    const __bf16* __restrict__ A, const __bf16* __restrict__ W,
    __bf16* __restrict__ xhb, __bf16* __restrict__ zsb, int M, int K)
{
    __shared__ __bf16 Als[128*AST2];
    __shared__ __bf16 Wls[128*AST2];
    const int tid = threadIdx.x;
    const int lane = tid & 63, w = tid >> 6;
    const int n0 = blockIdx.x*128, m0 = blockIdx.y*128;
    const int fr = lane & 15, fc = lane >> 4;
    const int row2 = tid >> 1, half = tid & 1;

    f32x4 acc[2][8] = {};

    for (int k0 = 0; k0 < K; k0 += 64) {
        bf16x8 av[4], wv[4];
        const bool aok = (m0 + row2) < M;
        const __bf16* asrc = A + (long)(m0+row2)*K + k0 + half*32;
        const __bf16* wsrc = W + (long)(n0+row2)*K + k0 + half*32;
        #pragma unroll
        for (int e = 0; e < 4; e++) {
            av[e] = aok ? *(const bf16x8*)(asrc + e*8) : (bf16x8){};
            wv[e] = *(const bf16x8*)(wsrc + e*8);
        }
        __syncthreads();
        #pragma unroll
        for (int e = 0; e < 4; e++) {
            *(bf16x8*)&Als[row2*AST2 + half*32 + e*8] = av[e];
            *(bf16x8*)&Wls[row2*AST2 + half*32 + e*8] = wv[e];
        }
        __syncthreads();
        #pragma unroll
        for (int s = 0; s < 2; s++) {
            bf16x8 a0 = *(const bf16x8*)&Als[(w*32 +      fr)*AST2 + s*32 + fc*8];
            bf16x8 a1 = *(const bf16x8*)&Als[(w*32 + 16 + fr)*AST2 + s*32 + fc*8];
            #pragma unroll
            for (int j = 0; j < 8; j++) {
                bf16x8 bv = *(const bf16x8*)&Wls[(j*16 + fr)*AST2 + s*32 + fc*8];
                acc[0][j] = __builtin_amdgcn_mfma_f32_16x16x32_bf16(a0, bv, acc[0][j], 0,0,0);
                acc[1][j] = __builtin_amdgcn_mfma_f32_16x16x32_bf16(a1, bv, acc[1][j], 0,0,0);
            }
        }
    }
    const bool xhalf = (n0 < 512);
    const int cbase = xhalf ? n0 : (n0 - 512);
    #pragma unroll
    for (int i = 0; i < 2; i++) {
        #pragma unroll
        for (int rr = 0; rr < 4; rr++) {
            int grow = m0 + w*32 + i*16 + fc*4 + rr;
            if (grow < M) {
                if (xhalf) {
                    #pragma unroll
                    for (int j = 0; j < 8; j++)
                        xhb[(long)grow*512 + cbase + j*16 + fr] = (__bf16)acc[i][j][rr];
                } else {
                    #pragma unroll
                    for (int j = 0; j < 8; j++)
                        zsb[(long)grow*512 + cbase + j*16 + fr] = (__bf16)siluf_(acc[i][j][rr]);
                }
            }
        }
    }
}

// ---------------------------------------------------------------------------
// dbc GEMM: [dt16 | BC] = xib[M,512] @ Wx[48,512]^T.  BM=64, 128 threads.
// ---------------------------------------------------------------------------
__global__ __launch_bounds__(128) void gemm_dbc(
    const __bf16* __restrict__ A, const __bf16* __restrict__ W,
    float* __restrict__ dt16, float* __restrict__ BC, int M)
{
    __shared__ __bf16 Als[64*ASTR];
    __shared__ __bf16 Wls[48*ASTR];
    const int tid = threadIdx.x;
    const int lane = tid & 63, w = tid >> 6;
    const int m0 = blockIdx.x*64;
    f32x4 acc[2][3] = {};

    const int arow = tid >> 1, ahalf = tid & 1;
    const int fr = lane & 15, fc = lane >> 4;

    for (int k0 = 0; k0 < 512; k0 += 32) {
        bf16x8 av0 = {}, av1 = {};
        if (m0 + arow < M) {
            const __bf16* src = A + (long)(m0+arow)*512 + k0 + ahalf*16;
            av0 = *(const bf16x8*)src;
            av1 = *(const bf16x8*)(src+8);
        }
        bf16x8 wv0 = {}, wv1 = {};
        if (tid < 96) {
            const __bf16* src = W + (long)(tid>>1)*512 + k0 + (tid&1)*16;
            wv0 = *(const bf16x8*)src;
            wv1 = *(const bf16x8*)(src+8);
        }
        __syncthreads();
        *(bf16x8*)&Als[arow*ASTR + ahalf*16]     = av0;
        *(bf16x8*)&Als[arow*ASTR + ahalf*16 + 8] = av1;
        if (tid < 96) {
            *(bf16x8*)&Wls[(tid>>1)*ASTR + (tid&1)*16]     = wv0;
            *(bf16x8*)&Wls[(tid>>1)*ASTR + (tid&1)*16 + 8] = wv1;
        }
        __syncthreads();

        bf16x8 a0 = *(const bf16x8*)&Als[(w*32 +      fr)*ASTR + fc*8];
        bf16x8 a1 = *(const bf16x8*)&Als[(w*32 + 16 + fr)*ASTR + fc*8];
        #pragma unroll
        for (int j = 0; j < 3; j++) {
            bf16x8 bv = *(const bf16x8*)&Wls[(j*16 + fr)*ASTR + fc*8];
            acc[0][j] = __builtin_amdgcn_mfma_f32_16x16x32_bf16(a0, bv, acc[0][j], 0,0,0);
            acc[1][j] = __builtin_amdgcn_mfma_f32_16x16x32_bf16(a1, bv, acc[1][j], 0,0,0);
        }
    }
    #pragma unroll
    for (int i = 0; i < 2; i++) {
        #pragma unroll
        for (int rr = 0; rr < 4; rr++) {
            long grow = m0 + w*32 + i*16 + fc*4 + rr;
            if (grow < M) {
                dt16[grow*16 + fr]    = acc[i][0][rr];
                BC[grow*32 + fr]      = acc[i][1][rr];
                BC[grow*32 + 16 + fr] = acc[i][2][rr];
            }
        }
    }
}

// ---------------------------------------------------------------------------
// delta: softplus(dt16 @ Wdt^T + bdt); pack (delta, xi) bf16 pair -> pdx u32.
// ---------------------------------------------------------------------------
__global__ __launch_bounds__(256) void delta_k(
    const float* __restrict__ dt16, const float* __restrict__ Wdt,
    const float* __restrict__ bdt, const __bf16* __restrict__ xib,
    unsigned* __restrict__ pdx)
{
    __shared__ float dtS[8*16];
    const int tid = threadIdx.x;
    const long r0 = (long)blockIdx.x*8;
    if (tid < 32) {
        long idx = r0*16 + tid*4;
        f32x4 v = (idx < (long)ROWS*16) ? *(const f32x4*)&dt16[idx] : (f32x4){};
        *(f32x4*)&dtS[tid*4] = v;
    }
    const int d0 = tid, d1 = tid + 256;
    f32x4 wa[4], wb[4];
    #pragma unroll
    for (int q = 0; q < 4; q++) {
        wa[q] = *(const f32x4*)(Wdt + d0*16 + q*4);
        wb[q] = *(const f32x4*)(Wdt + d1*16 + q*4);
    }
    const float b0 = bdt[d0], b1 = bdt[d1];
    __syncthreads();
    #pragma unroll
    for (int rr = 0; rr < 8; rr++) {
        long row = r0 + rr;
        if (row >= ROWS) return;
        const float* dt = &dtS[rr*16];
        float s0 = b0, s1 = b1;
        #pragma unroll
        for (int e = 0; e < 4; e++) {
            s0 += wa[0][e]*dt[e] + wa[1][e]*dt[4+e] + wa[2][e]*dt[8+e] + wa[3][e]*dt[12+e];
            s1 += wb[0][e]*dt[e] + wb[1][e]*dt[4+e] + wb[2][e]*dt[8+e] + wb[3][e]*dt[12+e];
        }
        float dl0 = (s0 > 20.f) ? s0 : log1pf(__expf(s0));
        float dl1 = (s1 > 20.f) ? s1 : log1pf(__expf(s1));
        unsigned x0 = __builtin_bit_cast(unsigned short, xib[row*512 + d0]);
        unsigned x1 = __builtin_bit_cast(unsigned short, xib[row*512 + d1]);
        pdx[row*512 + d0] = (unsigned)bfbits(dl0) | (x0 << 16);
        pdx[row*512 + d1] = (unsigned)bfbits(dl1) | (x1 << 16);
    }
}

// ---------------------------------------------------------------------------
// cls rows: out[b,c] = x[b,0,:] . cls_w[c,:] + cls_b[c] + skip -> xxb row q=0
// One WAVE per (b,c) output: 512 waves total.
// ---------------------------------------------------------------------------
__global__ __launch_bounds__(256) void cls_k(
    const float* __restrict__ x, const float* __restrict__ cls_w,
    const float* __restrict__ cls_b, const float* __restrict__ skip,
    __bf16* __restrict__ xxb)
{
    const int widx = blockIdx.x*4 + (threadIdx.x >> 6);   // 0..511
    const int lane = threadIdx.x & 63;
    const int b = widx >> 8, c = widx & 255;
    const float* xr = x + (long)b*1025*512 + lane*8;
    const float* wr = cls_w + (long)c*512 + lane*8;
    float4 xa = *(const float4*)xr,      xb4 = *(const float4*)(xr+4);
    float4 wa = *(const float4*)wr,      wb4 = *(const float4*)(wr+4);
    float s = xa.x*wa.x + xa.y*wa.y + xa.z*wa.z + xa.w*wa.w
            + xb4.x*wb4.x + xb4.y*wb4.y + xb4.z*wb4.z + xb4.w*wb4.w;
    #pragma unroll
    for (int o = 32; o > 0; o >>= 1) s += __shfl_xor(s, o);
    if (lane == 0) {
        long o = (long)b*L_TOT*256 + c;
        xxb[o] = (__bf16)(s + cls_b[c] + skip[o]);
    }
}

// ---------------------------------------------------------------------------
// Patch rearrange + LayerNorm(256) + skip add -> xxb; one wave per row.
// Handles only the 8192 patch rows (q >= 1).
// ---------------------------------------------------------------------------
__global__ __launch_bounds__(256) void rearrange_ln(
    const __bf16* __restrict__ e_buf, const float* __restrict__ ln_g,
    const float* __restrict__ ln_b, const float* __restrict__ skip,
    __bf16* __restrict__ xxb)
{
    const int wv = threadIdx.x >> 6, lane = threadIdx.x & 63;
    const int qg = blockIdx.x*4 + wv;          // 0..8191
    const int b = qg >> 12, q = (qg & 4095) + 1;
    const long obase = ((long)b*L_TOT + q)*256;

    const int t  = (q-1) >> 10;
    const int p  = (q-1) & 1023;
    const int h  = p >> 6;
    const int a  = (p >> 5) & 1;
    const int w_ = (p >> 1) & 15;
    const int bb = p & 1;
    const long tok = (long)b*1024 + t*256 + h*16 + w_;
    const __bf16* src = e_buf + tok*1024 + a*512 + bb*256 + lane*4;
    float v[4];
    {
        ushort2 u0 = *(const ushort2*)src;
        ushort2 u1 = *(const ushort2*)(src+2);
        v[0] = (float)__builtin_bit_cast(__bf16, u0.x);
        v[1] = (float)__builtin_bit_cast(__bf16, u0.y);
        v[2] = (float)__builtin_bit_cast(__bf16, u1.x);
        v[3] = (float)__builtin_bit_cast(__bf16, u1.y);
    }
    float s = v[0]+v[1]+v[2]+v[3];
    float s2 = v[0]*v[0]+v[1]*v[1]+v[2]*v[2]+v[3]*v[3];
    #pragma unroll
    for (int o = 32; o > 0; o >>= 1) { s += __shfl_xor(s, o); s2 += __shfl_xor(s2, o); }
    float mu = s * (1.f/256.f);
    float rs = rsqrtf(s2*(1.f/256.f) - mu*mu + 1e-5f);
    const int c0 = lane*4;
    float4 sk = *(const float4*)&skip[obase + c0];
    float skv[4] = {sk.x, sk.y, sk.z, sk.w};
    __bf16 ov[4];
    #pragma unroll
    for (int i = 0; i < 4; i++)
        ov[i] = (__bf16)((v[i] - mu)*rs*ln_g[c0+i] + ln_b[c0+i] + skv[i]);
    *(ushort2*)&xxb[obase + c0]     = make_ushort2(
        __builtin_bit_cast(unsigned short, ov[0]),
        __builtin_bit_cast(unsigned short, ov[1]));
    *(ushort2*)&xxb[obase + c0 + 2] = make_ushort2(
        __builtin_bit_cast(unsigned short, ov[2]),
        __builtin_bit_cast(unsigned short, ov[3]));
}

// ---------------------------------------------------------------------------
// Depthwise causal conv (k=4)+SiLU on x-half only; thread = 8 chans x 8 rows
// ---------------------------------------------------------------------------
__global__ __launch_bounds__(256) void conv_silu(
    const __bf16* __restrict__ xhb, const float* __restrict__ cw,
    const float* __restrict__ cb, __bf16* __restrict__ xib)
{
    const int tid = threadIdx.x;
    const int c = tid & 63;
    const long r0 = ((long)blockIdx.x*4 + (tid >> 6))*8;
    if (r0 >= ROWS) return;
    const int d0 = c*8;
    float wreg[4][8], breg[8];
    #pragma unroll
    for (int e = 0; e < 8; e++) {
        breg[e] = cb[d0+e];
        #pragma unroll
        for (int k = 0; k < 4; k++) wreg[k][e] = cw[(d0+e)*4 + k];
    }
    bf16x8 win[4];
    #pragma unroll
    for (int j = 0; j < 3; j++) {
        long rr = r0 - 3 + j;
        win[j] = (rr >= 0) ? *(const bf16x8*)&xhb[rr*512 + d0] : (bf16x8){};
    }
    #pragma unroll
    for (int rr = 0; rr < 8; rr++) {
        long rl = r0 + rr;
        if (rl >= ROWS) break;
        win[3] = *(const bf16x8*)&xhb[rl*512 + d0];
        int l = (int)(rl % L_TOT);
        float acc[8];
        #pragma unroll
        for (int e = 0; e < 8; e++) acc[e] = breg[e];
        #pragma unroll
        for (int k = 0; k < 4; k++) {
            if (l + k - 3 >= 0) {
                #pragma unroll
                for (int e = 0; e < 8; e++)
                    acc[e] += wreg[k][e]*(float)win[k][e];
            }
        }
        bf16x8 o;
        #pragma unroll
        for (int e = 0; e < 8; e++) o[e] = (__bf16)siluf_(acc[e]);
        *(bf16x8*)&xib[rl*512 + d0] = o;
        win[0] = win[1]; win[1] = win[2]; win[2] = win[3];
    }
}

// ---------------------------------------------------------------------------
// Segmented scan, LDS-staged. Block = (seg, b, 64-d group); 256 thr = 64d x 4ng
// ---------------------------------------------------------------------------
__global__ __launch_bounds__(256) void scan_p1(
    const unsigned* __restrict__ pdx,
    const float* __restrict__ BC, const float* __restrict__ A_log,
    float* __restrict__ segH, float* __restrict__ segP)
{
    __shared__ unsigned pdxS[SEGLEN*64];
    __shared__ float bS[SEGLEN*16];
    const int blk = blockIdx.x;
    const int seg = blk >> 4;
    const int b   = (blk >> 3) & 1;
    const int dbase = (blk & 7)*64;
    const int tid = threadIdx.x;
    const int l0 = seg*SEGLEN;
    const int nl = min(l0 + SEGLEN, L_TOT) - l0;
    const int nlc = nl > 0 ? nl : 0;

    for (int cc = tid; cc < nlc*16; cc += 256) {
        int l = cc >> 4, qq = cc & 15;
        *(uint4*)&pdxS[l*64 + qq*4] =
            *(const uint4*)&pdx[((long)b*L_TOT + l0 + l)*512 + dbase + qq*4];
    }
    for (int cc = tid; cc < nlc*4; cc += 256) {
        int l = cc >> 2, qq = cc & 3;
        *(f32x4*)&bS[l*16 + qq*4] =
            *(const f32x4*)&BC[((long)b*L_TOT + l0 + l)*32 + qq*4];
    }
    __syncthreads();

    const int dl_ = tid >> 2;
    const int d = dbase + dl_;
    const int ng = tid & 3;
    f32x4 Al = *(const f32x4*)(A_log + d*16 + ng*4);
    float Ar[4] = {-__expf(Al[0]), -__expf(Al[1]), -__expf(Al[2]), -__expf(Al[3])};
    float h[4] = {0,0,0,0};
    float P[4] = {1,1,1,1};
    for (int l = 0; l < nlc; l++) {
        unsigned v = pdxS[l*64 + dl_];
        float dl = __uint_as_float(v << 16);
        float xv = __uint_as_float(v & 0xffff0000u);
        f32x4 Bv = *(const f32x4*)&bS[l*16 + ng*4];
        float dx = dl*xv;
        #pragma unroll
        for (int n = 0; n < 4; n++) {
            float E = __expf(dl*Ar[n]);
            h[n] = h[n]*E + dx*Bv[n];
            P[n] *= E;
        }
    }
    long off = ((long)(seg*2 + b)*512 + d)*16 + ng*4;
    *(f32x4*)&segH[off] = f32x4{h[0],h[1],h[2],h[3]};
    *(f32x4*)&segP[off] = f32x4{P[0],P[1],P[2],P[3]};
}

__global__ __launch_bounds__(256) void scan_p2(
    float* __restrict__ segH, const float* __restrict__ segP)
{
    const int idx = blockIdx.x*256 + threadIdx.x;   // 16384
    float carry = 0.f;
    for (int s0 = 0; s0 < NSEG; s0 += 8) {
        float hh[8], pp[8];
        #pragma unroll
        for (int j = 0; j < 8; j++) {
            long o = (long)(s0+j)*16384 + idx;
            hh[j] = segH[o]; pp[j] = segP[o];
        }
        #pragma unroll
        for (int j = 0; j < 8; j++) {
            long o = (long)(s0+j)*16384 + idx;
            segH[o] = carry;
            carry = pp[j]*carry + hh[j];
        }
    }
}

__global__ __launch_bounds__(256) void scan_p3(
    const unsigned* __restrict__ pdx,
    const float* __restrict__ BC, const float* __restrict__ A_log,
    const float* __restrict__ segH, const float* __restrict__ Dp,
    const __bf16* __restrict__ zsb, __bf16* __restrict__ yb)
{
    __shared__ unsigned pdxS[SEGLEN*64];
    __shared__ float bcS[SEGLEN*32];
    __shared__ __bf16 zS[SEGLEN*64];
    __shared__ __bf16 yS[SEGLEN*64];
    const int blk = blockIdx.x;
    const int seg = blk >> 4;
    const int b   = (blk >> 3) & 1;
    const int dbase = (blk & 7)*64;
    const int tid = threadIdx.x;
    const int l0 = seg*SEGLEN;
    const int nl = min(l0 + SEGLEN, L_TOT) - l0;
    const int nlc = nl > 0 ? nl : 0;
    if (nlc == 0) return;

    for (int cc = tid; cc < nlc*16; cc += 256) {
        int l = cc >> 4, qq = cc & 15;
        *(uint4*)&pdxS[l*64 + qq*4] =
            *(const uint4*)&pdx[((long)b*L_TOT + l0 + l)*512 + dbase + qq*4];
    }
    for (int cc = tid; cc < nlc*8; cc += 256) {
        int l = cc >> 3, qq = cc & 7;
        *(f32x4*)&bcS[l*32 + qq*4] =
            *(const f32x4*)&BC[((long)b*L_TOT + l0 + l)*32 + qq*4];
    }
    for (int cc = tid; cc < nlc*8; cc += 256) {
        int l = cc >> 3, qq = cc & 7;
        *(bf16x8*)&zS[l*64 + qq*8] =
            *(const bf16x8*)&zsb[((long)b*L_TOT + l0 + l)*512 + dbase + qq*8];
    }
    __syncthreads();

    const int dl_ = tid >> 2;
    const int d = dbase + dl_;
    const int ng = tid & 3;
    f32x4 Al = *(const f32x4*)(A_log + d*16 + ng*4);
    float Ar[4] = {-__expf(Al[0]), -__expf(Al[1]), -__expf(Al[2]), -__expf(Al[3])};
    long off = ((long)(seg*2 + b)*512 + d)*16 + ng*4;
    f32x4 h4 = *(const f32x4*)&segH[off];
    float h[4] = {h4[0], h4[1], h4[2], h4[3]};
    const float Dd = Dp[d];
    for (int l = 0; l < nlc; l++) {
        unsigned v = pdxS[l*64 + dl_];
        float dl = __uint_as_float(v << 16);
        float xv = __uint_as_float(v & 0xffff0000u);
        f32x4 Bv = *(const f32x4*)&bcS[l*32 + ng*4];
        f32x4 Cv = *(const f32x4*)&bcS[l*32 + 16 + ng*4];
        float dx = dl*xv;
        float y = 0.f;
        #pragma unroll
        for (int n = 0; n < 4; n++) {
            float E = __expf(dl*Ar[n]);
            h[n] = h[n]*E + dx*Bv[n];
            y += h[n]*Cv[n];
        }
        y += __shfl_xor(y, 1);
        y += __shfl_xor(y, 2);
        if (ng == 0) {
            float z = (float)zS[l*64 + dl_];
            yS[l*64 + dl_] = (__bf16)((y + xv*Dd)*z);
        }
    }
    __syncthreads();
    for (int cc = tid; cc < nlc*8; cc += 256) {
        int l = cc >> 3, qq = cc & 7;
        *(bf16x8*)&yb[((long)b*L_TOT + l0 + l)*512 + dbase + qq*8] =
            *(bf16x8*)&yS[l*64 + qq*8];
    }
}

// ---------------------------------------------------------------------------
// BatchNorm over rows (bf16 input)
// ---------------------------------------------------------------------------
__global__ void zero_stats(float* __restrict__ stats) { stats[threadIdx.x] = 0.f; }

__global__ __launch_bounds__(256) void bn_reduce(
    const __bf16* __restrict__ xxb, float* __restrict__ stats)
{
    const int c = threadIdx.x;
    float s = 0.f, s2 = 0.f;
    for (int r = blockIdx.x; r < ROWS; r += gridDim.x) {
        float v = (float)xxb[(long)r*256 + c];
        s += v; s2 += v*v;
    }
    atomicAdd(&stats[c], s);
    atomicAdd(&stats[256 + c], s2);
}

__global__ __launch_bounds__(256) void bn_apply(
    const __bf16* __restrict__ xxb, const float* __restrict__ stats,
    const float* __restrict__ g, const float* __restrict__ bta,
    float* __restrict__ out)
{
    long idx = (long)blockIdx.x*256 + threadIdx.x;
    if (idx == 0) out[(long)ROWS*256] = 1024.0f;
    if (idx >= (long)ROWS*256) return;
    int c = (int)(idx & 255);
    float mu = stats[c] * (1.f/ROWS);
    float var = stats[256 + c] * (1.f/ROWS) - mu*mu;
    out[idx] = ((float)xxb[idx] - mu)*rsqrtf(var + 1e-5f)*g[c] + bta[c];
}

// ---------------------------------------------------------------------------
extern "C" void kernel_launch(void* const* d_in, const int* in_sizes, int n_in,
                              void* d_out, int out_size, void* d_ws, size_t ws_size,
                              hipStream_t stream)
{
    const float* x        = (const float*)d_in[0];
    const float* skip     = (const float*)d_in[1];
    const float* exp_w    = (const float*)d_in[2];
    const float* ln_g     = (const float*)d_in[3];
    const float* ln_b     = (const float*)d_in[4];
    const float* cls_w    = (const float*)d_in[5];
    const float* cls_b    = (const float*)d_in[6];
    const float* in_proj_w= (const float*)d_in[7];
    const float* conv_w   = (const float*)d_in[8];
    const float* conv_b   = (const float*)d_in[9];
    const float* xproj_w  = (const float*)d_in[10];
    const float* dt_w     = (const float*)d_in[11];
    const float* dt_b     = (const float*)d_in[12];
    const float* A_log    = (const float*)d_in[13];
    const float* Dp       = (const float*)d_in[14];
    const float* out_w    = (const float*)d_in[15];
    const float* bn_g     = (const float*)d_in[16];
    const float* bn_b     = (const float*)d_in[17];

    float* ws = (float*)d_ws;
    float* BC    = ws;                       //   262,208 f32
    float* dt16  = BC + 262208;              //   131,104 f32
    float* segH  = dt16 + 131104;            // 2,097,152 f32
    float* segP  = segH + 2097152;           // 2,097,152 f32
    float* stats = segP + 2097152;           //       512 f32
    unsigned* pdx = (unsigned*)(stats + 512);// 4,195,328 u32
    __bf16* expWb = (__bf16*)(pdx + 4195328);//   524,288
    __bf16* inWb  = expWb + 524288;          //   524,288
    __bf16* outWb = inWb + 524288;           //   262,144
    __bf16* xpWb  = outWb + 262144;          //    49,152
    __bf16* xxb   = xpWb + 49152;            // 2,097,664
    __bf16* xhb   = xxb + 2097664;           // 4,195,328  (e_b alias pre-loop)
    __bf16* e_b   = xhb;
    __bf16* zsb   = xhb + 4195328;           // 4,195,328
    __bf16* xib   = zsb + 4195328;           // 4,195,328  (Axb alias pre-loop)
    __bf16* Axb   = xib;
    __bf16* yb    = xib + 4195328;           // 4,195,328
    float* out    = (float*)d_out;

    cvt4<<<(1359872/8 + 255)/256, 256, 0, stream>>>(
        exp_w, in_proj_w, out_w, xproj_w, expWb, inWb, outWb, xpWb);
    cvt_gather_x<<<(1048576/8)/256, 256, 0, stream>>>(x, Axb);

    gemm_bf16<<<dim3(16, 16), 256, 0, stream>>>(
        Axb, expWb, e_b, 2048, 1024, 512);
    cls_k<<<128, 256, 0, stream>>>(x, cls_w, cls_b, skip, xxb);
    rearrange_ln<<<2048, 256, 0, stream>>>(e_b, ln_g, ln_b, skip, xxb);

    for (int layer = 0; layer < 2; layer++) {
        gemm_inproj<<<dim3(8, 65), 256, 0, stream>>>(
            xxb, inWb + layer*262144, xhb, zsb, ROWS, 256);
        conv_silu<<<(ROWS + 31)/32, 256, 0, stream>>>(
            xhb, conv_w + layer*512*4, conv_b + layer*512, xib);
        gemm_dbc<<<(ROWS + 63)/64, 128, 0, stream>>>(
            xib, xpWb + layer*24576, dt16, BC, ROWS);
        delta_k<<<(ROWS + 7)/8, 256, 0, stream>>>(
            dt16, dt_w + layer*512*16, dt_b + layer*512, xib, pdx);
        scan_p1<<<NSEG*16, 256, 0, stream>>>(
            pdx, BC, A_log + layer*512*16, segH, segP);
        scan_p2<<<64, 256, 0, stream>>>(segH, segP);
        scan_p3<<<NSEG*16, 256, 0, stream>>>(
            pdx, BC, A_log + layer*512*16, segH, Dp + layer*512, zsb, yb);
        gemm_bf16<<<dim3(4, 65), 256, 0, stream>>>(
            yb, outWb + layer*131072, xxb, ROWS, 256, 512);
    }

    zero_stats<<<1, 512, 0, stream>>>(stats);
    bn_reduce<<<128, 256, 0, stream>>>(xxb, stats);
    bn_apply<<<((long)ROWS*256 + 255)/256 + 1, 256, 0, stream>>>(
        xxb, stats, bn_g, bn_b, out);
}

// Round 10
// 376.735 us; speedup vs baseline: 1.3241x; 1.0406x over previous
//
#include <hip/hip_runtime.h>
#include <hip/hip_bf16.h>
#include <math.h>

#define L_TOT 4097
#define BSZ 2
#define ROWS (BSZ*L_TOT)   // 8194
#define NSEG 64
#define SEGLEN 65          // 64*65 = 4160 >= 4097

typedef __bf16 bf16x8 __attribute__((ext_vector_type(8)));
typedef float  f32x4  __attribute__((ext_vector_type(4)));
#define ASTR 56            // LDS row stride (bf16) for BK=32 staging tiles
#define AST2 72            // LDS row stride (bf16) for BK=64 staging tiles

__device__ __forceinline__ float sigmoidf_(float v){ return 1.0f/(1.0f+__expf(-v)); }
__device__ __forceinline__ float siluf_(float v){ return v * sigmoidf_(v); }
__device__ __forceinline__ unsigned short bfbits(float f){
    __bf16 h = (__bf16)f;
    return __builtin_bit_cast(unsigned short, h);
}

// ---------------------------------------------------------------------------
// prep: weight f32->bf16 (4 tensors), token gather->bf16, stats zeroing.
// blocks [0,664): cvt; block 664 also zeroes stats; blocks [664,1176): gather
// ---------------------------------------------------------------------------
__global__ __launch_bounds__(256) void prep_all(
    const float* __restrict__ w0, const float* __restrict__ w1,
    const float* __restrict__ w2, const float* __restrict__ w3,
    const float* __restrict__ x,
    __bf16* __restrict__ o0, __bf16* __restrict__ o1,
    __bf16* __restrict__ o2, __bf16* __restrict__ o3,
    __bf16* __restrict__ gx, float* __restrict__ stats)
{
    const int bid = blockIdx.x;
    if (bid < 664) {
        long i = ((long)bid*256 + threadIdx.x)*8;
        const float* src; __bf16* dst; long off;
        if (i < 524288)        { src = w0; dst = o0; off = i; }
        else if (i < 1048576)  { src = w1; dst = o1; off = i - 524288; }
        else if (i < 1310720)  { src = w2; dst = o2; off = i - 1048576; }
        else                   { src = w3; dst = o3; off = i - 1310720; }
        float4 a = *(const float4*)(src+off), b = *(const float4*)(src+off+4);
        bf16x8 o;
        o[0]=(__bf16)a.x; o[1]=(__bf16)a.y; o[2]=(__bf16)a.z; o[3]=(__bf16)a.w;
        o[4]=(__bf16)b.x; o[5]=(__bf16)b.y; o[6]=(__bf16)b.z; o[7]=(__bf16)b.w;
        *(bf16x8*)(dst+off) = o;
        return;
    }
    if (bid == 664) {
        stats[threadIdx.x] = 0.f;
        stats[threadIdx.x + 256] = 0.f;
    }
    long i = ((long)(bid-664)*256 + threadIdx.x)*8;
    if (i >= 2048L*512) return;
    int row = (int)(i >> 9), col = (int)(i & 511);
    long srow = row + (row >> 10) + 1;           // skip cls token per batch
    const float* src = x + srow*512 + col;
    float4 a = *(const float4*)src, b = *(const float4*)(src+4);
    bf16x8 o;
    o[0]=(__bf16)a.x; o[1]=(__bf16)a.y; o[2]=(__bf16)a.z; o[3]=(__bf16)a.w;
    o[4]=(__bf16)b.x; o[5]=(__bf16)b.y; o[6]=(__bf16)b.z; o[7]=(__bf16)b.w;
    *(bf16x8*)(gx+i) = o;
}

// ---------------------------------------------------------------------------
// bf16 MFMA GEMM (BM=128,BN=64,BK=32): C2[M,N] = A[M,K]*W[N,K]^T, bf16 out
// ---------------------------------------------------------------------------
__global__ __launch_bounds__(256) void gemm_bf16(
    const __bf16* __restrict__ A, const __bf16* __restrict__ W,
    __bf16* __restrict__ C2, int M, int N, int K)
{
    __shared__ __bf16 Als[128*ASTR];
    __shared__ __bf16 Wls[64*ASTR];
    const int tid = threadIdx.x;
    const int lane = tid & 63, w = tid >> 6;
    const int n0 = blockIdx.x*64, m0 = blockIdx.y*128;

    f32x4 acc[2][4] = {};
    const int arow = tid >> 1, ahalf = tid & 1;
    const int wrow = tid >> 2, wseg = tid & 3;
    const int fr = lane & 15, fc = lane >> 4;

    for (int k0 = 0; k0 < K; k0 += 32) {
        bf16x8 av0 = {}, av1 = {};
        if (m0 + arow < M) {
            const __bf16* src = A + (long)(m0+arow)*K + k0 + ahalf*16;
            av0 = *(const bf16x8*)src;
            av1 = *(const bf16x8*)(src+8);
        }
        bf16x8 wv = *(const bf16x8*)(W + (long)(n0+wrow)*K + k0 + wseg*8);
        __syncthreads();
        *(bf16x8*)&Als[arow*ASTR + ahalf*16]     = av0;
        *(bf16x8*)&Als[arow*ASTR + ahalf*16 + 8] = av1;
        *(bf16x8*)&Wls[wrow*ASTR + wseg*8]       = wv;
        __syncthreads();

        bf16x8 a0 = *(const bf16x8*)&Als[(w*32 +      fr)*ASTR + fc*8];
        bf16x8 a1 = *(const bf16x8*)&Als[(w*32 + 16 + fr)*ASTR + fc*8];
        #pragma unroll
        for (int j = 0; j < 4; j++) {
            bf16x8 bv = *(const bf16x8*)&Wls[(j*16 + fr)*ASTR + fc*8];
            acc[0][j] = __builtin_amdgcn_mfma_f32_16x16x32_bf16(a0, bv, acc[0][j], 0,0,0);
            acc[1][j] = __builtin_amdgcn_mfma_f32_16x16x32_bf16(a1, bv, acc[1][j], 0,0,0);
        }
    }
    #pragma unroll
    for (int i = 0; i < 2; i++) {
        #pragma unroll
        for (int rr = 0; rr < 4; rr++) {
            int grow = m0 + w*32 + i*16 + fc*4 + rr;
            if (grow < M) {
                #pragma unroll
                for (int j = 0; j < 4; j++)
                    C2[(long)grow*N + n0 + j*16 + fr] = (__bf16)acc[i][j][rr];
            }
        }
    }
}

// ---------------------------------------------------------------------------
// in_proj GEMM (BM=128,BN=128,BK=64, N=1024 fixed):
//   col<512 -> xhb raw bf16 [ROWS,512];  col>=512 -> zsb = silu(v) [ROWS,512]
// ---------------------------------------------------------------------------
__global__ __launch_bounds__(256) void gemm_inproj(
    const __bf16* __restrict__ A, const __bf16* __restrict__ W,
    __bf16* __restrict__ xhb, __bf16* __restrict__ zsb, int M, int K)
{
    __shared__ __bf16 Als[128*AST2];
    __shared__ __bf16 Wls[128*AST2];
    const int tid = threadIdx.x;
    const int lane = tid & 63, w = tid >> 6;
    const int n0 = blockIdx.x*128, m0 = blockIdx.y*128;
    const int fr = lane & 15, fc = lane >> 4;
    const int row2 = tid >> 1, half = tid & 1;

    f32x4 acc[2][8] = {};

    for (int k0 = 0; k0 < K; k0 += 64) {
        bf16x8 av[4], wv[4];
        const bool aok = (m0 + row2) < M;
        const __bf16* asrc = A + (long)(m0+row2)*K + k0 + half*32;
        const __bf16* wsrc = W + (long)(n0+row2)*K + k0 + half*32;
        #pragma unroll
        for (int e = 0; e < 4; e++) {
            av[e] = aok ? *(const bf16x8*)(asrc + e*8) : (bf16x8){};
            wv[e] = *(const bf16x8*)(wsrc + e*8);
        }
        __syncthreads();
        #pragma unroll
        for (int e = 0; e < 4; e++) {
            *(bf16x8*)&Als[row2*AST2 + half*32 + e*8] = av[e];
            *(bf16x8*)&Wls[row2*AST2 + half*32 + e*8] = wv[e];
        }
        __syncthreads();
        #pragma unroll
        for (int s = 0; s < 2; s++) {
            bf16x8 a0 = *(const bf16x8*)&Als[(w*32 +      fr)*AST2 + s*32 + fc*8];
            bf16x8 a1 = *(const bf16x8*)&Als[(w*32 + 16 + fr)*AST2 + s*32 + fc*8];
            #pragma unroll
            for (int j = 0; j < 8; j++) {
                bf16x8 bv = *(const bf16x8*)&Wls[(j*16 + fr)*AST2 + s*32 + fc*8];
                acc[0][j] = __builtin_amdgcn_mfma_f32_16x16x32_bf16(a0, bv, acc[0][j], 0,0,0);
                acc[1][j] = __builtin_amdgcn_mfma_f32_16x16x32_bf16(a1, bv, acc[1][j], 0,0,0);
            }
        }
    }
    const bool xhalf = (n0 < 512);
    const int cbase = xhalf ? n0 : (n0 - 512);
    #pragma unroll
    for (int i = 0; i < 2; i++) {
        #pragma unroll
        for (int rr = 0; rr < 4; rr++) {
            int grow = m0 + w*32 + i*16 + fc*4 + rr;
            if (grow < M) {
                if (xhalf) {
                    #pragma unroll
                    for (int j = 0; j < 8; j++)
                        xhb[(long)grow*512 + cbase + j*16 + fr] = (__bf16)acc[i][j][rr];
                } else {
                    #pragma unroll
                    for (int j = 0; j < 8; j++)
                        zsb[(long)grow*512 + cbase + j*16 + fr] = (__bf16)siluf_(acc[i][j][rr]);
                }
            }
        }
    }
}

// ---------------------------------------------------------------------------
// dbc GEMM: [dt16 | BC] = xib[M,512] @ Wx[48,512]^T. BM=64, 256 thr (4 waves,
// wave w -> rows w*16..w*16+15, 3 MFMA per K-step).
// ---------------------------------------------------------------------------
__global__ __launch_bounds__(256) void gemm_dbc(
    const __bf16* __restrict__ A, const __bf16* __restrict__ W,
    float* __restrict__ dt16, float* __restrict__ BC, int M)
{
    __shared__ __bf16 Als[64*ASTR];
    __shared__ __bf16 Wls[48*ASTR];
    const int tid = threadIdx.x;
    const int lane = tid & 63, w = tid >> 6;
    const int m0 = blockIdx.x*64;
    f32x4 acc[3] = {};

    const int arow = tid >> 2, aseg = tid & 3;   // 4 thr/row, 8 elems each
    const int fr = lane & 15, fc = lane >> 4;

    for (int k0 = 0; k0 < 512; k0 += 32) {
        bf16x8 av = {};
        if (m0 + arow < M)
            av = *(const bf16x8*)(A + (long)(m0+arow)*512 + k0 + aseg*8);
        bf16x8 wv = {};
        if (tid < 192)
            wv = *(const bf16x8*)(W + (long)(tid>>2)*512 + k0 + (tid&3)*8);
        __syncthreads();
        *(bf16x8*)&Als[arow*ASTR + aseg*8] = av;
        if (tid < 192) *(bf16x8*)&Wls[(tid>>2)*ASTR + (tid&3)*8] = wv;
        __syncthreads();

        bf16x8 a0 = *(const bf16x8*)&Als[(w*16 + fr)*ASTR + fc*8];
        #pragma unroll
        for (int j = 0; j < 3; j++) {
            bf16x8 bv = *(const bf16x8*)&Wls[(j*16 + fr)*ASTR + fc*8];
            acc[j] = __builtin_amdgcn_mfma_f32_16x16x32_bf16(a0, bv, acc[j], 0,0,0);
        }
    }
    #pragma unroll
    for (int rr = 0; rr < 4; rr++) {
        long grow = m0 + w*16 + fc*4 + rr;
        if (grow < M) {
            dt16[grow*16 + fr]    = acc[0][rr];
            BC[grow*32 + fr]      = acc[1][rr];
            BC[grow*32 + 16 + fr] = acc[2][rr];
        }
    }
}

// ---------------------------------------------------------------------------
// delta: softplus(dt16 @ Wdt^T + bdt); pack (delta, xi) bf16 pair -> pdx u32.
// ---------------------------------------------------------------------------
__global__ __launch_bounds__(256) void delta_k(
    const float* __restrict__ dt16, const float* __restrict__ Wdt,
    const float* __restrict__ bdt, const __bf16* __restrict__ xib,
    unsigned* __restrict__ pdx)
{
    __shared__ float dtS[8*16];
    const int tid = threadIdx.x;
    const long r0 = (long)blockIdx.x*8;
    if (tid < 32) {
        long idx = r0*16 + tid*4;
        f32x4 v = (idx < (long)ROWS*16) ? *(const f32x4*)&dt16[idx] : (f32x4){};
        *(f32x4*)&dtS[tid*4] = v;
    }
    const int d0 = tid, d1 = tid + 256;
    f32x4 wa[4], wb[4];
    #pragma unroll
    for (int q = 0; q < 4; q++) {
        wa[q] = *(const f32x4*)(Wdt + d0*16 + q*4);
        wb[q] = *(const f32x4*)(Wdt + d1*16 + q*4);
    }
    const float b0 = bdt[d0], b1 = bdt[d1];
    __syncthreads();
    #pragma unroll
    for (int rr = 0; rr < 8; rr++) {
        long row = r0 + rr;
        if (row >= ROWS) return;
        const float* dt = &dtS[rr*16];
        float s0 = b0, s1 = b1;
        #pragma unroll
        for (int e = 0; e < 4; e++) {
            s0 += wa[0][e]*dt[e] + wa[1][e]*dt[4+e] + wa[2][e]*dt[8+e] + wa[3][e]*dt[12+e];
            s1 += wb[0][e]*dt[e] + wb[1][e]*dt[4+e] + wb[2][e]*dt[8+e] + wb[3][e]*dt[12+e];
        }
        float dl0 = (s0 > 20.f) ? s0 : log1pf(__expf(s0));
        float dl1 = (s1 > 20.f) ? s1 : log1pf(__expf(s1));
        unsigned x0 = __builtin_bit_cast(unsigned short, xib[row*512 + d0]);
        unsigned x1 = __builtin_bit_cast(unsigned short, xib[row*512 + d1]);
        pdx[row*512 + d0] = (unsigned)bfbits(dl0) | (x0 << 16);
        pdx[row*512 + d1] = (unsigned)bfbits(dl1) | (x1 << 16);
    }
}

// ---------------------------------------------------------------------------
// Patch rearrange + LN(256) + skip -> xxb (blocks<2048); cls rows (blocks>=2048)
// ---------------------------------------------------------------------------
__global__ __launch_bounds__(256) void rearrange_ln_cls(
    const __bf16* __restrict__ e_buf, const float* __restrict__ x,
    const float* __restrict__ cls_w, const float* __restrict__ cls_b,
    const float* __restrict__ ln_g, const float* __restrict__ ln_b,
    const float* __restrict__ skip, __bf16* __restrict__ xxb)
{
    const int wv = threadIdx.x >> 6, lane = threadIdx.x & 63;
    if (blockIdx.x >= 2048) {
        // cls: one wave per (b,c) output, 512 waves
        const int widx = (blockIdx.x - 2048)*4 + wv;
        const int b = widx >> 8, c = widx & 255;
        const float* xr = x + (long)b*1025*512 + lane*8;
        const float* wr = cls_w + (long)c*512 + lane*8;
        float4 xa = *(const float4*)xr,  xb4 = *(const float4*)(xr+4);
        float4 wa = *(const float4*)wr,  wb4 = *(const float4*)(wr+4);
        float s = xa.x*wa.x + xa.y*wa.y + xa.z*wa.z + xa.w*wa.w
                + xb4.x*wb4.x + xb4.y*wb4.y + xb4.z*wb4.z + xb4.w*wb4.w;
        #pragma unroll
        for (int o = 32; o > 0; o >>= 1) s += __shfl_xor(s, o);
        if (lane == 0) {
            long o = (long)b*L_TOT*256 + c;
            xxb[o] = (__bf16)(s + cls_b[c] + skip[o]);
        }
        return;
    }
    const int qg = blockIdx.x*4 + wv;          // 0..8191
    const int b = qg >> 12, q = (qg & 4095) + 1;
    const long obase = ((long)b*L_TOT + q)*256;

    const int t  = (q-1) >> 10;
    const int p  = (q-1) & 1023;
    const int h  = p >> 6;
    const int a  = (p >> 5) & 1;
    const int w_ = (p >> 1) & 15;
    const int bb = p & 1;
    const long tok = (long)b*1024 + t*256 + h*16 + w_;
    const __bf16* src = e_buf + tok*1024 + a*512 + bb*256 + lane*4;
    float v[4];
    {
        ushort2 u0 = *(const ushort2*)src;
        ushort2 u1 = *(const ushort2*)(src+2);
        v[0] = (float)__builtin_bit_cast(__bf16, u0.x);
        v[1] = (float)__builtin_bit_cast(__bf16, u0.y);
        v[2] = (float)__builtin_bit_cast(__bf16, u1.x);
        v[3] = (float)__builtin_bit_cast(__bf16, u1.y);
    }
    float s = v[0]+v[1]+v[2]+v[3];
    float s2 = v[0]*v[0]+v[1]*v[1]+v[2]*v[2]+v[3]*v[3];
    #pragma unroll
    for (int o = 32; o > 0; o >>= 1) { s += __shfl_xor(s, o); s2 += __shfl_xor(s2, o); }
    float mu = s * (1.f/256.f);
    float rs = rsqrtf(s2*(1.f/256.f) - mu*mu + 1e-5f);
    const int c0 = lane*4;
    float4 sk = *(const float4*)&skip[obase + c0];
    float skv[4] = {sk.x, sk.y, sk.z, sk.w};
    __bf16 ov[4];
    #pragma unroll
    for (int i = 0; i < 4; i++)
        ov[i] = (__bf16)((v[i] - mu)*rs*ln_g[c0+i] + ln_b[c0+i] + skv[i]);
    *(ushort2*)&xxb[obase + c0]     = make_ushort2(
        __builtin_bit_cast(unsigned short, ov[0]),
        __builtin_bit_cast(unsigned short, ov[1]));
    *(ushort2*)&xxb[obase + c0 + 2] = make_ushort2(
        __builtin_bit_cast(unsigned short, ov[2]),
        __builtin_bit_cast(unsigned short, ov[3]));
}

// ---------------------------------------------------------------------------
// Depthwise causal conv (k=4)+SiLU on x-half only; thread = 8 chans x 8 rows
// ---------------------------------------------------------------------------
__global__ __launch_bounds__(256) void conv_silu(
    const __bf16* __restrict__ xhb, const float* __restrict__ cw,
    const float* __restrict__ cb, __bf16* __restrict__ xib)
{
    const int tid = threadIdx.x;
    const int c = tid & 63;
    const long r0 = ((long)blockIdx.x*4 + (tid >> 6))*8;
    if (r0 >= ROWS) return;
    const int d0 = c*8;
    float wreg[4][8], breg[8];
    #pragma unroll
    for (int e = 0; e < 8; e++) {
        breg[e] = cb[d0+e];
        #pragma unroll
        for (int k = 0; k < 4; k++) wreg[k][e] = cw[(d0+e)*4 + k];
    }
    bf16x8 win[4];
    #pragma unroll
    for (int j = 0; j < 3; j++) {
        long rr = r0 - 3 + j;
        win[j] = (rr >= 0) ? *(const bf16x8*)&xhb[rr*512 + d0] : (bf16x8){};
    }
    #pragma unroll
    for (int rr = 0; rr < 8; rr++) {
        long rl = r0 + rr;
        if (rl >= ROWS) break;
        win[3] = *(const bf16x8*)&xhb[rl*512 + d0];
        int l = (int)(rl % L_TOT);
        float acc[8];
        #pragma unroll
        for (int e = 0; e < 8; e++) acc[e] = breg[e];
        #pragma unroll
        for (int k = 0; k < 4; k++) {
            if (l + k - 3 >= 0) {
                #pragma unroll
                for (int e = 0; e < 8; e++)
                    acc[e] += wreg[k][e]*(float)win[k][e];
            }
        }
        bf16x8 o;
        #pragma unroll
        for (int e = 0; e < 8; e++) o[e] = (__bf16)siluf_(acc[e]);
        *(bf16x8*)&xib[rl*512 + d0] = o;
        win[0] = win[1]; win[1] = win[2]; win[2] = win[3];
    }
}

// ---------------------------------------------------------------------------
// Segmented scan, LDS-staged. Block = (seg, b, 64-d group); 256 thr = 64d x 4ng
// ---------------------------------------------------------------------------
__global__ __launch_bounds__(256) void scan_p1(
    const unsigned* __restrict__ pdx,
    const float* __restrict__ BC, const float* __restrict__ A_log,
    float* __restrict__ segH, float* __restrict__ segP)
{
    __shared__ unsigned pdxS[SEGLEN*64];
    __shared__ float bS[SEGLEN*16];
    const int blk = blockIdx.x;
    const int seg = blk >> 4;
    const int b   = (blk >> 3) & 1;
    const int dbase = (blk & 7)*64;
    const int tid = threadIdx.x;
    const int l0 = seg*SEGLEN;
    const int nl = min(l0 + SEGLEN, L_TOT) - l0;
    const int nlc = nl > 0 ? nl : 0;

    for (int cc = tid; cc < nlc*16; cc += 256) {
        int l = cc >> 4, qq = cc & 15;
        *(uint4*)&pdxS[l*64 + qq*4] =
            *(const uint4*)&pdx[((long)b*L_TOT + l0 + l)*512 + dbase + qq*4];
    }
    for (int cc = tid; cc < nlc*4; cc += 256) {
        int l = cc >> 2, qq = cc & 3;
        *(f32x4*)&bS[l*16 + qq*4] =
            *(const f32x4*)&BC[((long)b*L_TOT + l0 + l)*32 + qq*4];
    }
    __syncthreads();

    const int dl_ = tid >> 2;
    const int d = dbase + dl_;
    const int ng = tid & 3;
    f32x4 Al = *(const f32x4*)(A_log + d*16 + ng*4);
    float Ar[4] = {-__expf(Al[0]), -__expf(Al[1]), -__expf(Al[2]), -__expf(Al[3])};
    float h[4] = {0,0,0,0};
    float P[4] = {1,1,1,1};
    for (int l = 0; l < nlc; l++) {
        unsigned v = pdxS[l*64 + dl_];
        float dl = __uint_as_float(v << 16);
        float xv = __uint_as_float(v & 0xffff0000u);
        f32x4 Bv = *(const f32x4*)&bS[l*16 + ng*4];
        float dx = dl*xv;
        #pragma unroll
        for (int n = 0; n < 4; n++) {
            float E = __expf(dl*Ar[n]);
            h[n] = h[n]*E + dx*Bv[n];
            P[n] *= E;
        }
    }
    long off = ((long)(seg*2 + b)*512 + d)*16 + ng*4;
    *(f32x4*)&segH[off] = f32x4{h[0],h[1],h[2],h[3]};
    *(f32x4*)&segP[off] = f32x4{P[0],P[1],P[2],P[3]};
}

__global__ __launch_bounds__(256) void scan_p2(
    float* __restrict__ segH, const float* __restrict__ segP)
{
    const int idx = blockIdx.x*256 + threadIdx.x;   // 16384
    float carry = 0.f;
    for (int s0 = 0; s0 < NSEG; s0 += 8) {
        float hh[8], pp[8];
        #pragma unroll
        for (int j = 0; j < 8; j++) {
            long o = (long)(s0+j)*16384 + idx;
            hh[j] = segH[o]; pp[j] = segP[o];
        }
        #pragma unroll
        for (int j = 0; j < 8; j++) {
            long o = (long)(s0+j)*16384 + idx;
            segH[o] = carry;
            carry = pp[j]*carry + hh[j];
        }
    }
}

__global__ __launch_bounds__(256) void scan_p3(
    const unsigned* __restrict__ pdx,
    const float* __restrict__ BC, const float* __restrict__ A_log,
    const float* __restrict__ segH, const float* __restrict__ Dp,
    const __bf16* __restrict__ zsb, __bf16* __restrict__ yb)
{
    __shared__ unsigned pdxS[SEGLEN*64];   // low 16 bits become y after use
    __shared__ float bcS[SEGLEN*32];
    __shared__ __bf16 zS[SEGLEN*64];
    const int blk = blockIdx.x;
    const int seg = blk >> 4;
    const int b   = (blk >> 3) & 1;
    const int dbase = (blk & 7)*64;
    const int tid = threadIdx.x;
    const int l0 = seg*SEGLEN;
    const int nl = min(l0 + SEGLEN, L_TOT) - l0;
    const int nlc = nl > 0 ? nl : 0;
    if (nlc == 0) return;

    for (int cc = tid; cc < nlc*16; cc += 256) {
        int l = cc >> 4, qq = cc & 15;
        *(uint4*)&pdxS[l*64 + qq*4] =
            *(const uint4*)&pdx[((long)b*L_TOT + l0 + l)*512 + dbase + qq*4];
    }
    for (int cc = tid; cc < nlc*8; cc += 256) {
        int l = cc >> 3, qq = cc & 7;
        *(f32x4*)&bcS[l*32 + qq*4] =
            *(const f32x4*)&BC[((long)b*L_TOT + l0 + l)*32 + qq*4];
    }
    for (int cc = tid; cc < nlc*8; cc += 256) {
        int l = cc >> 3, qq = cc & 7;
        *(bf16x8*)&zS[l*64 + qq*8] =
            *(const bf16x8*)&zsb[((long)b*L_TOT + l0 + l)*512 + dbase + qq*8];
    }
    __syncthreads();

    const int dl_ = tid >> 2;
    const int d = dbase + dl_;
    const int ng = tid & 3;
    f32x4 Al = *(const f32x4*)(A_log + d*16 + ng*4);
    float Ar[4] = {-__expf(Al[0]), -__expf(Al[1]), -__expf(Al[2]), -__expf(Al[3])};
    long off = ((long)(seg*2 + b)*512 + d)*16 + ng*4;
    f32x4 h4 = *(const f32x4*)&segH[off];
    float h[4] = {h4[0], h4[1], h4[2], h4[3]};
    const float Dd = Dp[d];
    for (int l = 0; l < nlc; l++) {
        unsigned v = pdxS[l*64 + dl_];
        float dl = __uint_as_float(v << 16);
        float xv = __uint_as_float(v & 0xffff0000u);
        f32x4 Bv = *(const f32x4*)&bcS[l*32 + ng*4];
        f32x4 Cv = *(const f32x4*)&bcS[l*32 + 16 + ng*4];
        float dx = dl*xv;
        float y = 0.f;
        #pragma unroll
        for (int n = 0; n < 4; n++) {
            float E = __expf(dl*Ar[n]);
            h[n] = h[n]*E + dx*Bv[n];
            y += h[n]*Cv[n];
        }
        y += __shfl_xor(y, 1);
        y += __shfl_xor(y, 2);
        if (ng == 0) {
            // overlay y into low 16 bits of the consumed pdxS slot (column
            // ownership is per-wave; read-then-write in lockstep => race-free)
            float z = (float)zS[l*64 + dl_];
            ((unsigned short*)&pdxS[l*64 + dl_])[0] = bfbits((y + xv*Dd)*z);
        }
    }
    __syncthreads();
    for (int cc = tid; cc < nlc*8; cc += 256) {
        int l = cc >> 3, qq = cc & 7;
        bf16x8 o;
        #pragma unroll
        for (int e = 0; e < 8; e++)
            o[e] = __builtin_bit_cast(__bf16,
                       (unsigned short)(pdxS[l*64 + qq*8 + e] & 0xffffu));
        *(bf16x8*)&yb[((long)b*L_TOT + l0 + l)*512 + dbase + qq*8] = o;
    }
}

// ---------------------------------------------------------------------------
// BatchNorm over rows (bf16 input); stats zeroed in prep_all
// ---------------------------------------------------------------------------
__global__ __launch_bounds__(256) void bn_reduce(
    const __bf16* __restrict__ xxb, float* __restrict__ stats)
{
    const int c = threadIdx.x;
    float s = 0.f, s2 = 0.f;
    for (int r = blockIdx.x; r < ROWS; r += gridDim.x) {
        float v = (float)xxb[(long)r*256 + c];
        s += v; s2 += v*v;
    }
    atomicAdd(&stats[c], s);
    atomicAdd(&stats[256 + c], s2);
}

__global__ __launch_bounds__(256) void bn_apply(
    const __bf16* __restrict__ xxb, const float* __restrict__ stats,
    const float* __restrict__ g, const float* __restrict__ bta,
    float* __restrict__ out)
{
    long idx = (long)blockIdx.x*256 + threadIdx.x;
    if (idx == 0) out[(long)ROWS*256] = 1024.0f;
    if (idx >= (long)ROWS*256) return;
    int c = (int)(idx & 255);
    float mu = stats[c] * (1.f/ROWS);
    float var = stats[256 + c] * (1.f/ROWS) - mu*mu;
    out[idx] = ((float)xxb[idx] - mu)*rsqrtf(var + 1e-5f)*g[c] + bta[c];
}

// ---------------------------------------------------------------------------
extern "C" void kernel_launch(void* const* d_in, const int* in_sizes, int n_in,
                              void* d_out, int out_size, void* d_ws, size_t ws_size,
                              hipStream_t stream)
{
    const float* x        = (const float*)d_in[0];
    const float* skip     = (const float*)d_in[1];
    const float* exp_w    = (const float*)d_in[2];
    const float* ln_g     = (const float*)d_in[3];
    const float* ln_b     = (const float*)d_in[4];
    const float* cls_w    = (const float*)d_in[5];
    const float* cls_b    = (const float*)d_in[6];
    const float* in_proj_w= (const float*)d_in[7];
    const float* conv_w   = (const float*)d_in[8];
    const float* conv_b   = (const float*)d_in[9];
    const float* xproj_w  = (const float*)d_in[10];
    const float* dt_w     = (const float*)d_in[11];
    const float* dt_b     = (const float*)d_in[12];
    const float* A_log    = (const float*)d_in[13];
    const float* Dp       = (const float*)d_in[14];
    const float* out_w    = (const float*)d_in[15];
    const float* bn_g     = (const float*)d_in[16];
    const float* bn_b     = (const float*)d_in[17];

    float* ws = (float*)d_ws;
    float* BC    = ws;                       //   262,208 f32
    float* dt16  = BC + 262208;              //   131,104 f32
    float* segH  = dt16 + 131104;            // 1,048,576 f32 (NSEG=64)
    float* segP  = segH + 1048576;           // 1,048,576 f32
    float* stats = segP + 1048576;           //       512 f32
    unsigned* pdx = (unsigned*)(stats + 512);// 4,195,328 u32
    __bf16* expWb = (__bf16*)(pdx + 4195328);//   524,288
    __bf16* inWb  = expWb + 524288;          //   524,288
    __bf16* outWb = inWb + 524288;           //   262,144
    __bf16* xpWb  = outWb + 262144;          //    49,152
    __bf16* xxb   = xpWb + 49152;            // 2,097,664
    __bf16* xhb   = xxb + 2097664;           // 4,195,328  (e_b alias pre-loop)
    __bf16* e_b   = xhb;
    __bf16* zsb   = xhb + 4195328;           // 4,195,328
    __bf16* xib   = zsb + 4195328;           // 4,195,328  (Axb alias pre-loop)
    __bf16* Axb   = xib;
    __bf16* yb    = xib + 4195328;           // 4,195,328
    float* out    = (float*)d_out;

    prep_all<<<1176, 256, 0, stream>>>(
        exp_w, in_proj_w, out_w, xproj_w, x,
        expWb, inWb, outWb, xpWb, Axb, stats);

    gemm_bf16<<<dim3(16, 16), 256, 0, stream>>>(
        Axb, expWb, e_b, 2048, 1024, 512);
    rearrange_ln_cls<<<2176, 256, 0, stream>>>(
        e_b, x, cls_w, cls_b, ln_g, ln_b, skip, xxb);

    for (int layer = 0; layer < 2; layer++) {
        gemm_inproj<<<dim3(8, 65), 256, 0, stream>>>(
            xxb, inWb + layer*262144, xhb, zsb, ROWS, 256);
        conv_silu<<<(ROWS + 31)/32, 256, 0, stream>>>(
            xhb, conv_w + layer*512*4, conv_b + layer*512, xib);
        gemm_dbc<<<(ROWS + 63)/64, 256, 0, stream>>>(
            xib, xpWb + layer*24576, dt16, BC, ROWS);
        delta_k<<<(ROWS + 7)/8, 256, 0, stream>>>(
            dt16, dt_w + layer*512*16, dt_b + layer*512, xib, pdx);
        scan_p1<<<NSEG*16, 256, 0, stream>>>(
            pdx, BC, A_log + layer*512*16, segH, segP);
        scan_p2<<<64, 256, 0, stream>>>(segH, segP);
        scan_p3<<<NSEG*16, 256, 0, stream>>>(
            pdx, BC, A_log + layer*512*16, segH, Dp + layer*512, zsb, yb);
        gemm_bf16<<<dim3(4, 65), 256, 0, stream>>>(
            yb, outWb + layer*131072, xxb, ROWS, 256, 512);
    }

    bn_reduce<<<128, 256, 0, stream>>>(xxb, stats);
    bn_apply<<<((long)ROWS*256 + 255)/256 + 1, 256, 0, stream>>>(
        xxb, stats, bn_g, bn_b, out);
}